// Round 3
// baseline (1416.516 us; speedup 1.0000x reference)
//
#include <hip/hip_runtime.h>
#include <hip/hip_bf16.h>
#include <stdint.h>

#define BB 4
#define SS 4096
#define DD 256

typedef __attribute__((ext_vector_type(4))) float f32x4;
typedef __attribute__((ext_vector_type(8))) short s16x8;

__device__ __forceinline__ ushort f2bf(float f) {
  __hip_bfloat16 h = __float2bfloat16(f);
  return __builtin_bit_cast(ushort, h);
}

// ---------------- kernel 1: fp32 -> bf16 pack ----------------
__global__ void convert_kernel(const float* __restrict__ X,
                               const float* __restrict__ Wq,
                               const float* __restrict__ Wk,
                               const float* __restrict__ Wv,
                               const float* __restrict__ bq,
                               const float* __restrict__ bk,
                               const float* __restrict__ bv,
                               ushort* __restrict__ Xb,
                               ushort* __restrict__ Wb,
                               float* __restrict__ bias) {
  int tid = blockIdx.x * blockDim.x + threadIdx.x;
  int stride = gridDim.x * blockDim.x;
  const int NX4 = (BB * SS * DD) / 4;
  for (int i = tid; i < NX4; i += stride) {
    float4 v = ((const float4*)X)[i];
    ushort4 o = { f2bf(v.x), f2bf(v.y), f2bf(v.z), f2bf(v.w) };
    ((ushort4*)Xb)[i] = o;
  }
  const int NW4 = (DD * DD) / 4;
  for (int i = tid; i < NW4; i += stride) {
    float4 a = ((const float4*)Wq)[i];
    float4 b = ((const float4*)Wk)[i];
    float4 c = ((const float4*)Wv)[i];
    ushort4 oa = { f2bf(a.x), f2bf(a.y), f2bf(a.z), f2bf(a.w) };
    ushort4 ob = { f2bf(b.x), f2bf(b.y), f2bf(b.z), f2bf(b.w) };
    ushort4 oc = { f2bf(c.x), f2bf(c.y), f2bf(c.z), f2bf(c.w) };
    ((ushort4*)Wb)[i]           = oa;
    ((ushort4*)Wb)[NW4 + i]     = ob;
    ((ushort4*)Wb)[2 * NW4 + i] = oc;
  }
  if (tid < DD) {
    bias[tid]          = bq[tid];
    bias[DD + tid]     = bk[tid];
    bias[2 * DD + tid] = bv[tid];
  }
}

// ---------------- kernel 2: fused QKV projection GEMM ----------------
#define LROW 40  // padded LDS row stride (bf16 elems); 80B = 20 dwords -> 2-way bank alias (free)

__global__ __launch_bounds__(256) void proj_gemm(const ushort* __restrict__ Xb,
                                                 const ushort* __restrict__ Wb,
                                                 const float* __restrict__ bias,
                                                 ushort* __restrict__ Qb,
                                                 ushort* __restrict__ Kb,
                                                 ushort* __restrict__ Vt) {
  __shared__ ushort Al[128 * LROW];
  __shared__ ushort Bl[128 * LROW];
  const int m0 = blockIdx.x * 128;
  const int n0 = blockIdx.y * 128;
  const int t = threadIdx.x;
  const int lane = t & 63;
  const int w = t >> 6;
  const int wr = w & 1, wc = w >> 1;
  const int col = lane & 15;
  const int quad = lane >> 4;

  f32x4 acc[4][4];
#pragma unroll
  for (int i = 0; i < 4; i++)
#pragma unroll
    for (int j = 0; j < 4; j++) acc[i][j] = f32x4{0.f, 0.f, 0.f, 0.f};

  const int ci0 = t, ci1 = 256 + t;
  const int r0 = ci0 >> 2, c0 = ci0 & 3;
  const int r1 = ci1 >> 2, c1 = ci1 & 3;

  s16x8 pa0 = *(const s16x8*)(Xb + (m0 + r0) * DD + c0 * 8);
  s16x8 pa1 = *(const s16x8*)(Xb + (m0 + r1) * DD + c1 * 8);
  s16x8 pb0 = *(const s16x8*)(Wb + (n0 + r0) * DD + c0 * 8);
  s16x8 pb1 = *(const s16x8*)(Wb + (n0 + r1) * DD + c1 * 8);

  for (int kk = 0; kk < DD; kk += 32) {
    __syncthreads();
    *(s16x8*)&Al[r0 * LROW + c0 * 8] = pa0;
    *(s16x8*)&Al[r1 * LROW + c1 * 8] = pa1;
    *(s16x8*)&Bl[r0 * LROW + c0 * 8] = pb0;
    *(s16x8*)&Bl[r1 * LROW + c1 * 8] = pb1;
    __syncthreads();
    const int kn = kk + 32;
    if (kn < DD) {
      pa0 = *(const s16x8*)(Xb + (m0 + r0) * DD + kn + c0 * 8);
      pa1 = *(const s16x8*)(Xb + (m0 + r1) * DD + kn + c1 * 8);
      pb0 = *(const s16x8*)(Wb + (n0 + r0) * DD + kn + c0 * 8);
      pb1 = *(const s16x8*)(Wb + (n0 + r1) * DD + kn + c1 * 8);
    }
    s16x8 af[4], bfr[4];
#pragma unroll
    for (int mi = 0; mi < 4; mi++)
      af[mi] = *(const s16x8*)&Al[(wr * 64 + mi * 16 + col) * LROW + quad * 8];
#pragma unroll
    for (int ni = 0; ni < 4; ni++)
      bfr[ni] = *(const s16x8*)&Bl[(wc * 64 + ni * 16 + col) * LROW + quad * 8];
#pragma unroll
    for (int mi = 0; mi < 4; mi++)
#pragma unroll
      for (int ni = 0; ni < 4; ni++)
        acc[mi][ni] = __builtin_amdgcn_mfma_f32_16x16x32_bf16(af[mi], bfr[ni], acc[mi][ni], 0, 0, 0);
  }

  const int region = n0 >> 8;  // 0=Q, 1=K, 2=V
#pragma unroll
  for (int mi = 0; mi < 4; mi++) {
    const int gm = m0 + wr * 64 + mi * 16 + quad * 4;
#pragma unroll
    for (int ni = 0; ni < 4; ni++) {
      const int gn = n0 + wc * 64 + ni * 16 + col;
      const float bb = bias[gn];
      f32x4 v = acc[mi][ni];
      if (region == 0) {
#pragma unroll
        for (int rg = 0; rg < 4; rg++)
          Qb[(gm + rg) * DD + gn] = f2bf((v[rg] + bb) * 0.015625f);  // exact /64
      } else if (region == 1) {
        const int d = gn - 256;
#pragma unroll
        for (int rg = 0; rg < 4; rg++)
          Kb[(gm + rg) * DD + d] = f2bf(v[rg] + bb);
      } else {
        const int d = gn - 512;
        const int b = gm >> 12;
        const int s = gm & (SS - 1);
        ushort4 o = { f2bf(v[0] + bb), f2bf(v[1] + bb), f2bf(v[2] + bb), f2bf(v[3] + bb) };
        *(ushort4*)&Vt[((size_t)(b << 8) + d) * SS + s] = o;
      }
    }
  }
}

// ---------------- kernel 3: flash attention ----------------
// 1024 threads = 4 row-waves x 4 KV-split groups (16 waves -> 4 waves/SIMD).
// Group g owns KV tiles [g*1024, g*1024+1024) with private K/V LDS buffers;
// partials (m,l,O) merged via a 2-round LDS tree (1->0, 3->2, then 2->0).
#define NKT 32
#define KROW 260  // 520B = 130 dw, 130%32=2 -> 2-way alias (free)
#define VROW 36   //  72B =  18 dw, gcd(18,32)=2 -> 2-way
#define PROW 36

#define KL_U (NKT * KROW)        // 8320 ushorts per group
#define VL_U (DD * VROW)         // 9216 per group
#define PL_U (16 * PROW)         // 576 per wave
#define VOFF (4 * KL_U)          // 33280
#define POFF (VOFF + 4 * VL_U)   // 70144
#define SM_U (POFF + 16 * PL_U)  // 79360 ushorts = 158720 B (<= 160 KiB)

// exchange slot: 76 f32 (m[4], l[4], O[64], 16B-aligned stride); round 1 uses
// 512 slots = 155648 B <= 158720 B
#define XSTRIDE 76

__global__ __launch_bounds__(1024) void attn_kernel(const ushort* __restrict__ Qb,
                                                    const ushort* __restrict__ Kb,
                                                    const ushort* __restrict__ Vt,
                                                    const int* __restrict__ mask,
                                                    float* __restrict__ out) {
  __shared__ __align__(16) ushort sm[SM_U];

  const int qt = blockIdx.x;  // 0..63
  const int b = blockIdx.y;   // 0..3
  const int t = threadIdx.x;
  const int g = t >> 8;       // KV-split group: 0..3
  const int tg = t & 255;     // thread within group
  const int lane = t & 63;
  const int w = tg >> 6;      // row-wave within group: 0..3
  const int w16 = t >> 6;     // global wave: 0..15
  const int col = lane & 15;
  const int quad = lane >> 4;

  ushort* Kl = sm + g * KL_U;
  ushort* Vl = sm + VOFF + g * VL_U;
  ushort* Pw = sm + POFF + w16 * PL_U;

  const int q0 = qt * 64;
  const int qrow = q0 + w * 16;  // wave's first q row (within batch)

  // Q fragments (A-operand), pre-scaled by 1/64
  s16x8 qf[8];
  {
    const ushort* qp = Qb + ((size_t)b * SS + qrow + col) * DD + quad * 8;
#pragma unroll
    for (int dc = 0; dc < 8; dc++) qf[dc] = *(const s16x8*)(qp + dc * 32);
  }

  int kr[4], kc[4], vd[4], vc[4];
#pragma unroll
  for (int i = 0; i < 4; i++) {
    const int ci = i * 256 + tg;
    kr[i] = ci >> 5; kc[i] = ci & 31;  // K tile: 32 rows x 32 chunks(8)
    vd[i] = ci >> 2; vc[i] = ci & 3;   // Vt tile: 256 d-rows x 4 chunks(8)
  }

  const ushort* Kg = Kb + (size_t)b * SS * DD;
  const ushort* Vg = Vt + (size_t)b * DD * SS;
  const int* Mg = mask + ((size_t)b * SS + qrow + quad * 4) * SS;

  f32x4 Oc[16];
#pragma unroll
  for (int i = 0; i < 16; i++) Oc[i] = f32x4{0.f, 0.f, 0.f, 0.f};
  float m_i[4] = {-INFINITY, -INFINITY, -INFINITY, -INFINITY};
  float l_i[4] = {0.f, 0.f, 0.f, 0.f};

  const int NT4 = (SS / NKT) / 4;  // 32 tiles per group
  const int kb0 = g * NT4 * NKT;   // group's first kv position

  // prefetch this group's tile 0 into registers
  s16x8 pk[4], pv[4];
  int pm[2][4];
#pragma unroll
  for (int i = 0; i < 4; i++) {
    pk[i] = *(const s16x8*)(Kg + (size_t)(kb0 + kr[i]) * DD + kc[i] * 8);
    pv[i] = *(const s16x8*)(Vg + (size_t)vd[i] * SS + kb0 + vc[i] * 8);
  }
#pragma unroll
  for (int jt = 0; jt < 2; jt++)
#pragma unroll
    for (int rg = 0; rg < 4; rg++) pm[jt][rg] = Mg[rg * SS + kb0 + jt * 16 + col];

  for (int tt = 0; tt < NT4; tt++) {
    __syncthreads();
#pragma unroll
    for (int i = 0; i < 4; i++) {
      *(s16x8*)&Kl[kr[i] * KROW + kc[i] * 8] = pk[i];
      *(s16x8*)&Vl[vd[i] * VROW + vc[i] * 8] = pv[i];
    }
    __syncthreads();
    int mcur[2][4];
#pragma unroll
    for (int jt = 0; jt < 2; jt++)
#pragma unroll
      for (int rg = 0; rg < 4; rg++) mcur[jt][rg] = pm[jt][rg];
    if (tt + 1 < NT4) {
      const int k0n = kb0 + (tt + 1) * NKT;
#pragma unroll
      for (int i = 0; i < 4; i++) {
        pk[i] = *(const s16x8*)(Kg + ((size_t)k0n + kr[i]) * DD + kc[i] * 8);
        pv[i] = *(const s16x8*)(Vg + (size_t)vd[i] * SS + k0n + vc[i] * 8);
      }
#pragma unroll
      for (int jt = 0; jt < 2; jt++)
#pragma unroll
        for (int rg = 0; rg < 4; rg++) pm[jt][rg] = Mg[rg * SS + k0n + jt * 16 + col];
    }

    // S = Q K^T (pre-scaled): 2 col-tiles x 8 d-chunks
    f32x4 st[2];
    __builtin_amdgcn_s_setprio(1);
#pragma unroll
    for (int jt = 0; jt < 2; jt++) {
      f32x4 s = f32x4{0.f, 0.f, 0.f, 0.f};
#pragma unroll
      for (int dc = 0; dc < 8; dc++) {
        s16x8 kb = *(const s16x8*)&Kl[(jt * 16 + col) * KROW + dc * 32 + quad * 8];
        s = __builtin_amdgcn_mfma_f32_16x16x32_bf16(qf[dc], kb, s, 0, 0, 0);
      }
      st[jt] = s;
    }
    __builtin_amdgcn_s_setprio(0);
    // mask (nonzero -> -1e9, post-scale, matching reference)
#pragma unroll
    for (int jt = 0; jt < 2; jt++)
#pragma unroll
      for (int rg = 0; rg < 4; rg++)
        if (mcur[jt][rg]) st[jt][rg] = -1e9f;

    // online softmax: per q-row (row = quad*4+rg), reduce over 16 col lanes
    float al[4];
#pragma unroll
    for (int rg = 0; rg < 4; rg++) {
      float v = fmaxf(st[0][rg], st[1][rg]);
      v = fmaxf(v, __shfl_xor(v, 1));
      v = fmaxf(v, __shfl_xor(v, 2));
      v = fmaxf(v, __shfl_xor(v, 4));
      v = fmaxf(v, __shfl_xor(v, 8));
      const float mn = fmaxf(m_i[rg], v);
      al[rg] = __expf(m_i[rg] - mn);
      m_i[rg] = mn;
    }
#pragma unroll
    for (int rg = 0; rg < 4; rg++) {
      const float p0 = __expf(st[0][rg] - m_i[rg]);
      const float p1 = __expf(st[1][rg] - m_i[rg]);
      st[0][rg] = p0; st[1][rg] = p1;
      float s2 = p0 + p1;
      s2 += __shfl_xor(s2, 1);
      s2 += __shfl_xor(s2, 2);
      s2 += __shfl_xor(s2, 4);
      s2 += __shfl_xor(s2, 8);
      l_i[rg] = l_i[rg] * al[rg] + s2;
    }
#pragma unroll
    for (int dt = 0; dt < 16; dt++)
#pragma unroll
      for (int rg = 0; rg < 4; rg++) Oc[dt][rg] *= al[rg];

    // P: C-layout -> LDS -> A-layout (per-wave region, same-wave dependency only)
#pragma unroll
    for (int jt = 0; jt < 2; jt++)
#pragma unroll
      for (int rg = 0; rg < 4; rg++)
        Pw[(quad * 4 + rg) * PROW + jt * 16 + col] = f2bf(st[jt][rg]);
    s16x8 pa = *(const s16x8*)&Pw[col * PROW + quad * 8];

    // O += P * V
    __builtin_amdgcn_s_setprio(1);
#pragma unroll
    for (int dt = 0; dt < 16; dt++) {
      s16x8 vb = *(const s16x8*)&Vl[(dt * 16 + col) * VROW + quad * 8];
      Oc[dt] = __builtin_amdgcn_mfma_f32_16x16x32_bf16(pa, vb, Oc[dt], 0, 0, 0);
    }
    __builtin_amdgcn_s_setprio(0);
  }

  // ---- 2-round merge of the 4 KV-split partials (exact online-softmax) ----
  float* ex = (float*)sm;
  // round 1: g1 -> pair slot 0, g3 -> pair slot 1; g0 merges 1, g2 merges 3
  __syncthreads();
  if (g & 1) {
    float* slot = ex + (size_t)((g >> 1) * 256 + w * 64 + lane) * XSTRIDE;
#pragma unroll
    for (int rg = 0; rg < 4; rg++) { slot[rg] = m_i[rg]; slot[4 + rg] = l_i[rg]; }
#pragma unroll
    for (int dt = 0; dt < 16; dt++) *(f32x4*)&slot[8 + dt * 4] = Oc[dt];
  }
  __syncthreads();
  if (!(g & 1)) {
    const float* slot = ex + (size_t)((g >> 1) * 256 + w * 64 + lane) * XSTRIDE;
    float a0[4], a1[4];
#pragma unroll
    for (int rg = 0; rg < 4; rg++) {
      const float m1 = slot[rg];
      const float l1 = slot[4 + rg];
      const float mm = fmaxf(m_i[rg], m1);
      a0[rg] = __expf(m_i[rg] - mm);
      a1[rg] = __expf(m1 - mm);
      m_i[rg] = mm;
      l_i[rg] = l_i[rg] * a0[rg] + l1 * a1[rg];
    }
#pragma unroll
    for (int dt = 0; dt < 16; dt++) {
      const f32x4 o1 = *(const f32x4*)&slot[8 + dt * 4];
#pragma unroll
      for (int rg = 0; rg < 4; rg++)
        Oc[dt][rg] = Oc[dt][rg] * a0[rg] + o1[rg] * a1[rg];
    }
  }
  // round 2: g2 -> slot area 0; g0 merges and stores
  __syncthreads();
  if (g == 2) {
    float* slot = ex + (size_t)(w * 64 + lane) * XSTRIDE;
#pragma unroll
    for (int rg = 0; rg < 4; rg++) { slot[rg] = m_i[rg]; slot[4 + rg] = l_i[rg]; }
#pragma unroll
    for (int dt = 0; dt < 16; dt++) *(f32x4*)&slot[8 + dt * 4] = Oc[dt];
  }
  __syncthreads();
  if (g == 0) {
    const float* slot = ex + (size_t)(w * 64 + lane) * XSTRIDE;
    float a0[4], a1[4], inv[4];
#pragma unroll
    for (int rg = 0; rg < 4; rg++) {
      const float m1 = slot[rg];
      const float l1 = slot[4 + rg];
      const float mm = fmaxf(m_i[rg], m1);
      a0[rg] = __expf(m_i[rg] - mm);
      a1[rg] = __expf(m1 - mm);
      inv[rg] = 1.0f / (l_i[rg] * a0[rg] + l1 * a1[rg]);
    }
    float* op = out + ((size_t)b * SS + qrow + quad * 4) * DD;
#pragma unroll
    for (int dt = 0; dt < 16; dt++) {
      const f32x4 o1 = *(const f32x4*)&slot[8 + dt * 4];
#pragma unroll
      for (int rg = 0; rg < 4; rg++)
        op[rg * DD + dt * 16 + col] = (Oc[dt][rg] * a0[rg] + o1[rg] * a1[rg]) * inv[rg];
    }
  }
}

extern "C" void kernel_launch(void* const* d_in, const int* in_sizes, int n_in,
                              void* d_out, int out_size, void* d_ws, size_t ws_size,
                              hipStream_t stream) {
  const float* X  = (const float*)d_in[0];
  const int* mask = (const int*)d_in[1];
  const float* Wq = (const float*)d_in[2];
  const float* bq = (const float*)d_in[3];
  const float* Wk = (const float*)d_in[4];
  const float* bk = (const float*)d_in[5];
  const float* Wv = (const float*)d_in[6];
  const float* bv = (const float*)d_in[7];
  float* out = (float*)d_out;

  ushort* base = (ushort*)d_ws;
  ushort* Xb = base;
  ushort* Wb = Xb + (size_t)BB * SS * DD;
  ushort* Qb = Wb + (size_t)3 * DD * DD;
  ushort* Kb = Qb + (size_t)BB * SS * DD;
  ushort* Vt = Kb + (size_t)BB * SS * DD;
  float* bias = (float*)(Vt + (size_t)BB * SS * DD);

  convert_kernel<<<1024, 256, 0, stream>>>(X, Wq, Wk, Wv, bq, bk, bv, Xb, Wb, bias);
  proj_gemm<<<dim3(128, 6), 256, 0, stream>>>(Xb, Wb, bias, Qb, Kb, Vt);
  attn_kernel<<<dim3(64, 4), 1024, 0, stream>>>(Qb, Kb, Vt, mask, out);
}

// Round 4
// 1414.308 us; speedup vs baseline: 1.0016x; 1.0016x over previous
//
#include <hip/hip_runtime.h>
#include <hip/hip_bf16.h>
#include <stdint.h>

#define BB 4
#define SS 4096
#define DD 256

typedef __attribute__((ext_vector_type(4))) float f32x4;
typedef __attribute__((ext_vector_type(8))) short s16x8;

__device__ __forceinline__ ushort f2bf(float f) {
  __hip_bfloat16 h = __float2bfloat16(f);
  return __builtin_bit_cast(ushort, h);
}

// ---------------- kernel 1: fp32 -> bf16 pack ----------------
__global__ void convert_kernel(const float* __restrict__ X,
                               const float* __restrict__ Wq,
                               const float* __restrict__ Wk,
                               const float* __restrict__ Wv,
                               const float* __restrict__ bq,
                               const float* __restrict__ bk,
                               const float* __restrict__ bv,
                               ushort* __restrict__ Xb,
                               ushort* __restrict__ Wb,
                               float* __restrict__ bias) {
  int tid = blockIdx.x * blockDim.x + threadIdx.x;
  int stride = gridDim.x * blockDim.x;
  const int NX4 = (BB * SS * DD) / 4;
  for (int i = tid; i < NX4; i += stride) {
    float4 v = ((const float4*)X)[i];
    ushort4 o = { f2bf(v.x), f2bf(v.y), f2bf(v.z), f2bf(v.w) };
    ((ushort4*)Xb)[i] = o;
  }
  const int NW4 = (DD * DD) / 4;
  for (int i = tid; i < NW4; i += stride) {
    float4 a = ((const float4*)Wq)[i];
    float4 b = ((const float4*)Wk)[i];
    float4 c = ((const float4*)Wv)[i];
    ushort4 oa = { f2bf(a.x), f2bf(a.y), f2bf(a.z), f2bf(a.w) };
    ushort4 ob = { f2bf(b.x), f2bf(b.y), f2bf(b.z), f2bf(b.w) };
    ushort4 oc = { f2bf(c.x), f2bf(c.y), f2bf(c.z), f2bf(c.w) };
    ((ushort4*)Wb)[i]           = oa;
    ((ushort4*)Wb)[NW4 + i]     = ob;
    ((ushort4*)Wb)[2 * NW4 + i] = oc;
  }
  if (tid < DD) {
    bias[tid]          = bq[tid];
    bias[DD + tid]     = bk[tid];
    bias[2 * DD + tid] = bv[tid];
  }
}

// ---------------- kernel 2: fused QKV projection GEMM ----------------
#define LROW 40  // padded LDS row stride (bf16 elems); 80B = 20 dwords -> 2-way bank alias (free)

__global__ __launch_bounds__(256) void proj_gemm(const ushort* __restrict__ Xb,
                                                 const ushort* __restrict__ Wb,
                                                 const float* __restrict__ bias,
                                                 ushort* __restrict__ Qb,
                                                 ushort* __restrict__ Kb,
                                                 ushort* __restrict__ Vt) {
  __shared__ ushort Al[128 * LROW];
  __shared__ ushort Bl[128 * LROW];
  const int m0 = blockIdx.x * 128;
  const int n0 = blockIdx.y * 128;
  const int t = threadIdx.x;
  const int lane = t & 63;
  const int w = t >> 6;
  const int wr = w & 1, wc = w >> 1;
  const int col = lane & 15;
  const int quad = lane >> 4;

  f32x4 acc[4][4];
#pragma unroll
  for (int i = 0; i < 4; i++)
#pragma unroll
    for (int j = 0; j < 4; j++) acc[i][j] = f32x4{0.f, 0.f, 0.f, 0.f};

  const int ci0 = t, ci1 = 256 + t;
  const int r0 = ci0 >> 2, c0 = ci0 & 3;
  const int r1 = ci1 >> 2, c1 = ci1 & 3;

  s16x8 pa0 = *(const s16x8*)(Xb + (m0 + r0) * DD + c0 * 8);
  s16x8 pa1 = *(const s16x8*)(Xb + (m0 + r1) * DD + c1 * 8);
  s16x8 pb0 = *(const s16x8*)(Wb + (n0 + r0) * DD + c0 * 8);
  s16x8 pb1 = *(const s16x8*)(Wb + (n0 + r1) * DD + c1 * 8);

  for (int kk = 0; kk < DD; kk += 32) {
    __syncthreads();
    *(s16x8*)&Al[r0 * LROW + c0 * 8] = pa0;
    *(s16x8*)&Al[r1 * LROW + c1 * 8] = pa1;
    *(s16x8*)&Bl[r0 * LROW + c0 * 8] = pb0;
    *(s16x8*)&Bl[r1 * LROW + c1 * 8] = pb1;
    __syncthreads();
    const int kn = kk + 32;
    if (kn < DD) {
      pa0 = *(const s16x8*)(Xb + (m0 + r0) * DD + kn + c0 * 8);
      pa1 = *(const s16x8*)(Xb + (m0 + r1) * DD + kn + c1 * 8);
      pb0 = *(const s16x8*)(Wb + (n0 + r0) * DD + kn + c0 * 8);
      pb1 = *(const s16x8*)(Wb + (n0 + r1) * DD + kn + c1 * 8);
    }
    s16x8 af[4], bfr[4];
#pragma unroll
    for (int mi = 0; mi < 4; mi++)
      af[mi] = *(const s16x8*)&Al[(wr * 64 + mi * 16 + col) * LROW + quad * 8];
#pragma unroll
    for (int ni = 0; ni < 4; ni++)
      bfr[ni] = *(const s16x8*)&Bl[(wc * 64 + ni * 16 + col) * LROW + quad * 8];
#pragma unroll
    for (int mi = 0; mi < 4; mi++)
#pragma unroll
      for (int ni = 0; ni < 4; ni++)
        acc[mi][ni] = __builtin_amdgcn_mfma_f32_16x16x32_bf16(af[mi], bfr[ni], acc[mi][ni], 0, 0, 0);
  }

  const int region = n0 >> 8;  // 0=Q, 1=K, 2=V
#pragma unroll
  for (int mi = 0; mi < 4; mi++) {
    const int gm = m0 + wr * 64 + mi * 16 + quad * 4;
#pragma unroll
    for (int ni = 0; ni < 4; ni++) {
      const int gn = n0 + wc * 64 + ni * 16 + col;
      const float bb = bias[gn];
      f32x4 v = acc[mi][ni];
      if (region == 0) {
#pragma unroll
        for (int rg = 0; rg < 4; rg++)
          Qb[(gm + rg) * DD + gn] = f2bf((v[rg] + bb) * 0.015625f);  // exact /64
      } else if (region == 1) {
        const int d = gn - 256;
#pragma unroll
        for (int rg = 0; rg < 4; rg++)
          Kb[(gm + rg) * DD + d] = f2bf(v[rg] + bb);
      } else {
        const int d = gn - 512;
        const int b = gm >> 12;
        const int s = gm & (SS - 1);
        ushort4 o = { f2bf(v[0] + bb), f2bf(v[1] + bb), f2bf(v[2] + bb), f2bf(v[3] + bb) };
        *(ushort4*)&Vt[((size_t)(b << 8) + d) * SS + s] = o;
      }
    }
  }
}

// ---------------- kernel 3: flash attention ----------------
// 1024 threads = 4 row-waves x 4 KV-split groups (16 waves -> 4 waves/SIMD).
// __launch_bounds__(1024, 4): 4 waves/EU -> 128-VGPR cap. Without the explicit
// second arg the compiler targeted 8 waves/EU (64 VGPR) and spilled the f32
// accumulators to scratch: 4 GB of HBM spill traffic, 5x regression (R3).
#define NKT 32
#define KROW 260  // 520B = 130 dw, 130%32=2 -> 2-way alias (free)
#define VROW 36   //  72B =  18 dw, gcd(18,32)=2 -> 2-way
#define PROW 36

#define KL_U (NKT * KROW)        // 8320 ushorts per group
#define VL_U (DD * VROW)         // 9216 per group
#define PL_U (16 * PROW)         // 576 per wave
#define VOFF (4 * KL_U)          // 33280
#define POFF (VOFF + 4 * VL_U)   // 70144
#define SM_U (POFF + 16 * PL_U)  // 79360 ushorts = 158720 B (<= 160 KiB)

// exchange slot: 76 f32 (m[4], l[4], O[64], 16B-aligned stride); round 1 uses
// 512 slots = 155648 B <= 158720 B
#define XSTRIDE 76

__global__ __launch_bounds__(1024, 4) void attn_kernel(const ushort* __restrict__ Qb,
                                                       const ushort* __restrict__ Kb,
                                                       const ushort* __restrict__ Vt,
                                                       const int* __restrict__ mask,
                                                       float* __restrict__ out) {
  __shared__ __align__(16) ushort sm[SM_U];

  const int qt = blockIdx.x;  // 0..63
  const int b = blockIdx.y;   // 0..3
  const int t = threadIdx.x;
  const int g = t >> 8;       // KV-split group: 0..3
  const int tg = t & 255;     // thread within group
  const int lane = t & 63;
  const int w = tg >> 6;      // row-wave within group: 0..3
  const int w16 = t >> 6;     // global wave: 0..15
  const int col = lane & 15;
  const int quad = lane >> 4;

  ushort* Kl = sm + g * KL_U;
  ushort* Vl = sm + VOFF + g * VL_U;
  ushort* Pw = sm + POFF + w16 * PL_U;

  const int q0 = qt * 64;
  const int qrow = q0 + w * 16;  // wave's first q row (within batch)

  // Q fragments (A-operand), pre-scaled by 1/64
  s16x8 qf[8];
  {
    const ushort* qp = Qb + ((size_t)b * SS + qrow + col) * DD + quad * 8;
#pragma unroll
    for (int dc = 0; dc < 8; dc++) qf[dc] = *(const s16x8*)(qp + dc * 32);
  }

  int kr[4], kc[4], vd[4], vc[4];
#pragma unroll
  for (int i = 0; i < 4; i++) {
    const int ci = i * 256 + tg;
    kr[i] = ci >> 5; kc[i] = ci & 31;  // K tile: 32 rows x 32 chunks(8)
    vd[i] = ci >> 2; vc[i] = ci & 3;   // Vt tile: 256 d-rows x 4 chunks(8)
  }

  const ushort* Kg = Kb + (size_t)b * SS * DD;
  const ushort* Vg = Vt + (size_t)b * DD * SS;
  const int* Mg = mask + ((size_t)b * SS + qrow + quad * 4) * SS;

  f32x4 Oc[16];
#pragma unroll
  for (int i = 0; i < 16; i++) Oc[i] = f32x4{0.f, 0.f, 0.f, 0.f};
  float m_i[4] = {-INFINITY, -INFINITY, -INFINITY, -INFINITY};
  float l_i[4] = {0.f, 0.f, 0.f, 0.f};

  const int NT4 = (SS / NKT) / 4;  // 32 tiles per group
  const int kb0 = g * NT4 * NKT;   // group's first kv position

  // prefetch this group's tile 0 into registers
  s16x8 pk[4], pv[4];
  int pm[2][4];
#pragma unroll
  for (int i = 0; i < 4; i++) {
    pk[i] = *(const s16x8*)(Kg + (size_t)(kb0 + kr[i]) * DD + kc[i] * 8);
    pv[i] = *(const s16x8*)(Vg + (size_t)vd[i] * SS + kb0 + vc[i] * 8);
  }
#pragma unroll
  for (int jt = 0; jt < 2; jt++)
#pragma unroll
    for (int rg = 0; rg < 4; rg++) pm[jt][rg] = Mg[rg * SS + kb0 + jt * 16 + col];

  for (int tt = 0; tt < NT4; tt++) {
    __syncthreads();
#pragma unroll
    for (int i = 0; i < 4; i++) {
      *(s16x8*)&Kl[kr[i] * KROW + kc[i] * 8] = pk[i];
      *(s16x8*)&Vl[vd[i] * VROW + vc[i] * 8] = pv[i];
    }
    __syncthreads();
    int mcur[2][4];
#pragma unroll
    for (int jt = 0; jt < 2; jt++)
#pragma unroll
      for (int rg = 0; rg < 4; rg++) mcur[jt][rg] = pm[jt][rg];
    if (tt + 1 < NT4) {
      const int k0n = kb0 + (tt + 1) * NKT;
#pragma unroll
      for (int i = 0; i < 4; i++) {
        pk[i] = *(const s16x8*)(Kg + ((size_t)k0n + kr[i]) * DD + kc[i] * 8);
        pv[i] = *(const s16x8*)(Vg + (size_t)vd[i] * SS + k0n + vc[i] * 8);
      }
#pragma unroll
      for (int jt = 0; jt < 2; jt++)
#pragma unroll
        for (int rg = 0; rg < 4; rg++) pm[jt][rg] = Mg[rg * SS + k0n + jt * 16 + col];
    }

    // S = Q K^T (pre-scaled): 2 col-tiles x 8 d-chunks
    f32x4 st[2];
    __builtin_amdgcn_s_setprio(1);
#pragma unroll
    for (int jt = 0; jt < 2; jt++) {
      f32x4 s = f32x4{0.f, 0.f, 0.f, 0.f};
#pragma unroll
      for (int dc = 0; dc < 8; dc++) {
        s16x8 kb = *(const s16x8*)&Kl[(jt * 16 + col) * KROW + dc * 32 + quad * 8];
        s = __builtin_amdgcn_mfma_f32_16x16x32_bf16(qf[dc], kb, s, 0, 0, 0);
      }
      st[jt] = s;
    }
    __builtin_amdgcn_s_setprio(0);
    // mask (nonzero -> -1e9, post-scale, matching reference)
#pragma unroll
    for (int jt = 0; jt < 2; jt++)
#pragma unroll
      for (int rg = 0; rg < 4; rg++)
        if (mcur[jt][rg]) st[jt][rg] = -1e9f;

    // online softmax: per q-row (row = quad*4+rg), reduce over 16 col lanes
    float al[4];
#pragma unroll
    for (int rg = 0; rg < 4; rg++) {
      float v = fmaxf(st[0][rg], st[1][rg]);
      v = fmaxf(v, __shfl_xor(v, 1));
      v = fmaxf(v, __shfl_xor(v, 2));
      v = fmaxf(v, __shfl_xor(v, 4));
      v = fmaxf(v, __shfl_xor(v, 8));
      const float mn = fmaxf(m_i[rg], v);
      al[rg] = __expf(m_i[rg] - mn);
      m_i[rg] = mn;
    }
#pragma unroll
    for (int rg = 0; rg < 4; rg++) {
      const float p0 = __expf(st[0][rg] - m_i[rg]);
      const float p1 = __expf(st[1][rg] - m_i[rg]);
      st[0][rg] = p0; st[1][rg] = p1;
      float s2 = p0 + p1;
      s2 += __shfl_xor(s2, 1);
      s2 += __shfl_xor(s2, 2);
      s2 += __shfl_xor(s2, 4);
      s2 += __shfl_xor(s2, 8);
      l_i[rg] = l_i[rg] * al[rg] + s2;
    }
#pragma unroll
    for (int dt = 0; dt < 16; dt++)
#pragma unroll
      for (int rg = 0; rg < 4; rg++) Oc[dt][rg] *= al[rg];

    // P: C-layout -> LDS -> A-layout (per-wave region, same-wave dependency only)
#pragma unroll
    for (int jt = 0; jt < 2; jt++)
#pragma unroll
      for (int rg = 0; rg < 4; rg++)
        Pw[(quad * 4 + rg) * PROW + jt * 16 + col] = f2bf(st[jt][rg]);
    s16x8 pa = *(const s16x8*)&Pw[col * PROW + quad * 8];

    // O += P * V
    __builtin_amdgcn_s_setprio(1);
#pragma unroll
    for (int dt = 0; dt < 16; dt++) {
      s16x8 vb = *(const s16x8*)&Vl[(dt * 16 + col) * VROW + quad * 8];
      Oc[dt] = __builtin_amdgcn_mfma_f32_16x16x32_bf16(pa, vb, Oc[dt], 0, 0, 0);
    }
    __builtin_amdgcn_s_setprio(0);
  }

  // ---- 2-round merge of the 4 KV-split partials (exact online-softmax) ----
  float* ex = (float*)sm;
  // round 1: g1 -> pair slot 0, g3 -> pair slot 1; g0 merges 1, g2 merges 3
  __syncthreads();
  if (g & 1) {
    float* slot = ex + (size_t)((g >> 1) * 256 + w * 64 + lane) * XSTRIDE;
#pragma unroll
    for (int rg = 0; rg < 4; rg++) { slot[rg] = m_i[rg]; slot[4 + rg] = l_i[rg]; }
#pragma unroll
    for (int dt = 0; dt < 16; dt++) *(f32x4*)&slot[8 + dt * 4] = Oc[dt];
  }
  __syncthreads();
  if (!(g & 1)) {
    const float* slot = ex + (size_t)((g >> 1) * 256 + w * 64 + lane) * XSTRIDE;
    float a0[4], a1[4];
#pragma unroll
    for (int rg = 0; rg < 4; rg++) {
      const float m1 = slot[rg];
      const float l1 = slot[4 + rg];
      const float mm = fmaxf(m_i[rg], m1);
      a0[rg] = __expf(m_i[rg] - mm);
      a1[rg] = __expf(m1 - mm);
      m_i[rg] = mm;
      l_i[rg] = l_i[rg] * a0[rg] + l1 * a1[rg];
    }
#pragma unroll
    for (int dt = 0; dt < 16; dt++) {
      const f32x4 o1 = *(const f32x4*)&slot[8 + dt * 4];
#pragma unroll
      for (int rg = 0; rg < 4; rg++)
        Oc[dt][rg] = Oc[dt][rg] * a0[rg] + o1[rg] * a1[rg];
    }
  }
  // round 2: g2 -> slot area 0; g0 merges and stores
  __syncthreads();
  if (g == 2) {
    float* slot = ex + (size_t)(w * 64 + lane) * XSTRIDE;
#pragma unroll
    for (int rg = 0; rg < 4; rg++) { slot[rg] = m_i[rg]; slot[4 + rg] = l_i[rg]; }
#pragma unroll
    for (int dt = 0; dt < 16; dt++) *(f32x4*)&slot[8 + dt * 4] = Oc[dt];
  }
  __syncthreads();
  if (g == 0) {
    const float* slot = ex + (size_t)(w * 64 + lane) * XSTRIDE;
    float a0[4], a1[4], inv[4];
#pragma unroll
    for (int rg = 0; rg < 4; rg++) {
      const float m1 = slot[rg];
      const float l1 = slot[4 + rg];
      const float mm = fmaxf(m_i[rg], m1);
      a0[rg] = __expf(m_i[rg] - mm);
      a1[rg] = __expf(m1 - mm);
      inv[rg] = 1.0f / (l_i[rg] * a0[rg] + l1 * a1[rg]);
    }
    float* op = out + ((size_t)b * SS + qrow + quad * 4) * DD;
#pragma unroll
    for (int dt = 0; dt < 16; dt++) {
      const f32x4 o1 = *(const f32x4*)&slot[8 + dt * 4];
#pragma unroll
      for (int rg = 0; rg < 4; rg++)
        op[rg * DD + dt * 16 + col] = (Oc[dt][rg] * a0[rg] + o1[rg] * a1[rg]) * inv[rg];
    }
  }
}

extern "C" void kernel_launch(void* const* d_in, const int* in_sizes, int n_in,
                              void* d_out, int out_size, void* d_ws, size_t ws_size,
                              hipStream_t stream) {
  const float* X  = (const float*)d_in[0];
  const int* mask = (const int*)d_in[1];
  const float* Wq = (const float*)d_in[2];
  const float* bq = (const float*)d_in[3];
  const float* Wk = (const float*)d_in[4];
  const float* bk = (const float*)d_in[5];
  const float* Wv = (const float*)d_in[6];
  const float* bv = (const float*)d_in[7];
  float* out = (float*)d_out;

  ushort* base = (ushort*)d_ws;
  ushort* Xb = base;
  ushort* Wb = Xb + (size_t)BB * SS * DD;
  ushort* Qb = Wb + (size_t)3 * DD * DD;
  ushort* Kb = Qb + (size_t)BB * SS * DD;
  ushort* Vt = Kb + (size_t)BB * SS * DD;
  float* bias = (float*)(Vt + (size_t)BB * SS * DD);

  convert_kernel<<<1024, 256, 0, stream>>>(X, Wq, Wk, Wv, bq, bk, bv, Xb, Wb, bias);
  proj_gemm<<<dim3(128, 6), 256, 0, stream>>>(Xb, Wb, bias, Qb, Kb, Vt);
  attn_kernel<<<dim3(64, 4), 1024, 0, stream>>>(Qb, Kb, Vt, mask, out);
}

// Round 5
// 1414.178 us; speedup vs baseline: 1.0017x; 1.0001x over previous
//
#include <hip/hip_runtime.h>
#include <hip/hip_bf16.h>
#include <stdint.h>

#define BB 4
#define SS 4096
#define DD 256

typedef __attribute__((ext_vector_type(4))) float f32x4;
typedef __attribute__((ext_vector_type(8))) short s16x8;

__device__ __forceinline__ ushort f2bf(float f) {
  __hip_bfloat16 h = __float2bfloat16(f);
  return __builtin_bit_cast(ushort, h);
}

// ---------------- kernel 1: fp32 -> bf16 pack ----------------
__global__ void convert_kernel(const float* __restrict__ X,
                               const float* __restrict__ Wq,
                               const float* __restrict__ Wk,
                               const float* __restrict__ Wv,
                               const float* __restrict__ bq,
                               const float* __restrict__ bk,
                               const float* __restrict__ bv,
                               ushort* __restrict__ Xb,
                               ushort* __restrict__ Wb,
                               float* __restrict__ bias) {
  int tid = blockIdx.x * blockDim.x + threadIdx.x;
  int stride = gridDim.x * blockDim.x;
  const int NX4 = (BB * SS * DD) / 4;
  for (int i = tid; i < NX4; i += stride) {
    float4 v = ((const float4*)X)[i];
    ushort4 o = { f2bf(v.x), f2bf(v.y), f2bf(v.z), f2bf(v.w) };
    ((ushort4*)Xb)[i] = o;
  }
  const int NW4 = (DD * DD) / 4;
  for (int i = tid; i < NW4; i += stride) {
    float4 a = ((const float4*)Wq)[i];
    float4 b = ((const float4*)Wk)[i];
    float4 c = ((const float4*)Wv)[i];
    ushort4 oa = { f2bf(a.x), f2bf(a.y), f2bf(a.z), f2bf(a.w) };
    ushort4 ob = { f2bf(b.x), f2bf(b.y), f2bf(b.z), f2bf(b.w) };
    ushort4 oc = { f2bf(c.x), f2bf(c.y), f2bf(c.z), f2bf(c.w) };
    ((ushort4*)Wb)[i]           = oa;
    ((ushort4*)Wb)[NW4 + i]     = ob;
    ((ushort4*)Wb)[2 * NW4 + i] = oc;
  }
  if (tid < DD) {
    bias[tid]          = bq[tid];
    bias[DD + tid]     = bk[tid];
    bias[2 * DD + tid] = bv[tid];
  }
}

// ---------------- kernel 2: fused QKV projection GEMM ----------------
#define LROW 40  // padded LDS row stride (bf16 elems); 80B = 20 dwords -> 2-way bank alias (free)

__global__ __launch_bounds__(256) void proj_gemm(const ushort* __restrict__ Xb,
                                                 const ushort* __restrict__ Wb,
                                                 const float* __restrict__ bias,
                                                 ushort* __restrict__ Qb,
                                                 ushort* __restrict__ Kb,
                                                 ushort* __restrict__ Vt) {
  __shared__ ushort Al[128 * LROW];
  __shared__ ushort Bl[128 * LROW];
  const int m0 = blockIdx.x * 128;
  const int n0 = blockIdx.y * 128;
  const int t = threadIdx.x;
  const int lane = t & 63;
  const int w = t >> 6;
  const int wr = w & 1, wc = w >> 1;
  const int col = lane & 15;
  const int quad = lane >> 4;

  f32x4 acc[4][4];
#pragma unroll
  for (int i = 0; i < 4; i++)
#pragma unroll
    for (int j = 0; j < 4; j++) acc[i][j] = f32x4{0.f, 0.f, 0.f, 0.f};

  const int ci0 = t, ci1 = 256 + t;
  const int r0 = ci0 >> 2, c0 = ci0 & 3;
  const int r1 = ci1 >> 2, c1 = ci1 & 3;

  s16x8 pa0 = *(const s16x8*)(Xb + (m0 + r0) * DD + c0 * 8);
  s16x8 pa1 = *(const s16x8*)(Xb + (m0 + r1) * DD + c1 * 8);
  s16x8 pb0 = *(const s16x8*)(Wb + (n0 + r0) * DD + c0 * 8);
  s16x8 pb1 = *(const s16x8*)(Wb + (n0 + r1) * DD + c1 * 8);

  for (int kk = 0; kk < DD; kk += 32) {
    __syncthreads();
    *(s16x8*)&Al[r0 * LROW + c0 * 8] = pa0;
    *(s16x8*)&Al[r1 * LROW + c1 * 8] = pa1;
    *(s16x8*)&Bl[r0 * LROW + c0 * 8] = pb0;
    *(s16x8*)&Bl[r1 * LROW + c1 * 8] = pb1;
    __syncthreads();
    const int kn = kk + 32;
    if (kn < DD) {
      pa0 = *(const s16x8*)(Xb + (m0 + r0) * DD + kn + c0 * 8);
      pa1 = *(const s16x8*)(Xb + (m0 + r1) * DD + kn + c1 * 8);
      pb0 = *(const s16x8*)(Wb + (n0 + r0) * DD + kn + c0 * 8);
      pb1 = *(const s16x8*)(Wb + (n0 + r1) * DD + kn + c1 * 8);
    }
    s16x8 af[4], bfr[4];
#pragma unroll
    for (int mi = 0; mi < 4; mi++)
      af[mi] = *(const s16x8*)&Al[(wr * 64 + mi * 16 + col) * LROW + quad * 8];
#pragma unroll
    for (int ni = 0; ni < 4; ni++)
      bfr[ni] = *(const s16x8*)&Bl[(wc * 64 + ni * 16 + col) * LROW + quad * 8];
#pragma unroll
    for (int mi = 0; mi < 4; mi++)
#pragma unroll
      for (int ni = 0; ni < 4; ni++)
        acc[mi][ni] = __builtin_amdgcn_mfma_f32_16x16x32_bf16(af[mi], bfr[ni], acc[mi][ni], 0, 0, 0);
  }

  const int region = n0 >> 8;  // 0=Q, 1=K, 2=V
#pragma unroll
  for (int mi = 0; mi < 4; mi++) {
    const int gm = m0 + wr * 64 + mi * 16 + quad * 4;
#pragma unroll
    for (int ni = 0; ni < 4; ni++) {
      const int gn = n0 + wc * 64 + ni * 16 + col;
      const float bb = bias[gn];
      f32x4 v = acc[mi][ni];
      if (region == 0) {
#pragma unroll
        for (int rg = 0; rg < 4; rg++)
          Qb[(gm + rg) * DD + gn] = f2bf((v[rg] + bb) * 0.015625f);  // exact /64
      } else if (region == 1) {
        const int d = gn - 256;
#pragma unroll
        for (int rg = 0; rg < 4; rg++)
          Kb[(gm + rg) * DD + d] = f2bf(v[rg] + bb);
      } else {
        const int d = gn - 512;
        const int b = gm >> 12;
        const int s = gm & (SS - 1);
        ushort4 o = { f2bf(v[0] + bb), f2bf(v[1] + bb), f2bf(v[2] + bb), f2bf(v[3] + bb) };
        *(ushort4*)&Vt[((size_t)(b << 8) + d) * SS + s] = o;
      }
    }
  }
}

// ---------------- kernel 3: flash attention ----------------
// 1024 threads = 4 row-waves x 4 KV-split groups (16 waves -> 4 waves/SIMD).
// OCCUPANCY PIN: hipcc's default register heuristic targets 2 WGs/CU; at
// 1024 threads that is 8 waves/EU -> 64-VGPR cap -> f32 accumulators spill
// to scratch (R3/R4: 4 GB HBM spill traffic, 5x regression). launch_bounds'
// 2nd arg only sets the MIN waves/EU (4 <= 8, no effect). amdgpu_waves_per_eu
// (4,4) pins the MAX too: cap 512/4 = 128 VGPR, kernel needs ~110, no spill.
#define NKT 32
#define KROW 260  // 520B = 130 dw, 130%32=2 -> 2-way alias (free)
#define VROW 36   //  72B =  18 dw, gcd(18,32)=2 -> 2-way
#define PROW 36

#define KL_U (NKT * KROW)        // 8320 ushorts per group
#define VL_U (DD * VROW)         // 9216 per group
#define PL_U (16 * PROW)         // 576 per wave
#define VOFF (4 * KL_U)          // 33280
#define POFF (VOFF + 4 * VL_U)   // 70144
#define SM_U (POFF + 16 * PL_U)  // 79360 ushorts = 158720 B (<= 160 KiB)

// exchange slot: 76 f32 (m[4], l[4], O[64], 16B-aligned stride); round 1 uses
// 512 slots = 155648 B <= 158720 B
#define XSTRIDE 76

__global__ __launch_bounds__(1024)
__attribute__((amdgpu_waves_per_eu(4, 4)))
void attn_kernel(const ushort* __restrict__ Qb,
                 const ushort* __restrict__ Kb,
                 const ushort* __restrict__ Vt,
                 const int* __restrict__ mask,
                 float* __restrict__ out) {
  __shared__ __align__(16) ushort sm[SM_U];

  const int qt = blockIdx.x;  // 0..63
  const int b = blockIdx.y;   // 0..3
  const int t = threadIdx.x;
  const int g = t >> 8;       // KV-split group: 0..3
  const int tg = t & 255;     // thread within group
  const int lane = t & 63;
  const int w = tg >> 6;      // row-wave within group: 0..3
  const int w16 = t >> 6;     // global wave: 0..15
  const int col = lane & 15;
  const int quad = lane >> 4;

  ushort* Kl = sm + g * KL_U;
  ushort* Vl = sm + VOFF + g * VL_U;
  ushort* Pw = sm + POFF + w16 * PL_U;

  const int q0 = qt * 64;
  const int qrow = q0 + w * 16;  // wave's first q row (within batch)

  // Q fragments (A-operand), pre-scaled by 1/64
  s16x8 qf[8];
  {
    const ushort* qp = Qb + ((size_t)b * SS + qrow + col) * DD + quad * 8;
#pragma unroll
    for (int dc = 0; dc < 8; dc++) qf[dc] = *(const s16x8*)(qp + dc * 32);
  }

  int kr[4], kc[4], vd[4], vc[4];
#pragma unroll
  for (int i = 0; i < 4; i++) {
    const int ci = i * 256 + tg;
    kr[i] = ci >> 5; kc[i] = ci & 31;  // K tile: 32 rows x 32 chunks(8)
    vd[i] = ci >> 2; vc[i] = ci & 3;   // Vt tile: 256 d-rows x 4 chunks(8)
  }

  const ushort* Kg = Kb + (size_t)b * SS * DD;
  const ushort* Vg = Vt + (size_t)b * DD * SS;
  const int* Mg = mask + ((size_t)b * SS + qrow + quad * 4) * SS;

  f32x4 Oc[16];
#pragma unroll
  for (int i = 0; i < 16; i++) Oc[i] = f32x4{0.f, 0.f, 0.f, 0.f};
  float m_i[4] = {-INFINITY, -INFINITY, -INFINITY, -INFINITY};
  float l_i[4] = {0.f, 0.f, 0.f, 0.f};

  const int NT4 = (SS / NKT) / 4;  // 32 tiles per group
  const int kb0 = g * NT4 * NKT;   // group's first kv position

  // prefetch this group's tile 0 into registers
  s16x8 pk[4], pv[4];
  int pm[2][4];
#pragma unroll
  for (int i = 0; i < 4; i++) {
    pk[i] = *(const s16x8*)(Kg + (size_t)(kb0 + kr[i]) * DD + kc[i] * 8);
    pv[i] = *(const s16x8*)(Vg + (size_t)vd[i] * SS + kb0 + vc[i] * 8);
  }
#pragma unroll
  for (int jt = 0; jt < 2; jt++)
#pragma unroll
    for (int rg = 0; rg < 4; rg++) pm[jt][rg] = Mg[rg * SS + kb0 + jt * 16 + col];

  for (int tt = 0; tt < NT4; tt++) {
    __syncthreads();
#pragma unroll
    for (int i = 0; i < 4; i++) {
      *(s16x8*)&Kl[kr[i] * KROW + kc[i] * 8] = pk[i];
      *(s16x8*)&Vl[vd[i] * VROW + vc[i] * 8] = pv[i];
    }
    __syncthreads();
    int mcur[2][4];
#pragma unroll
    for (int jt = 0; jt < 2; jt++)
#pragma unroll
      for (int rg = 0; rg < 4; rg++) mcur[jt][rg] = pm[jt][rg];
    if (tt + 1 < NT4) {
      const int k0n = kb0 + (tt + 1) * NKT;
#pragma unroll
      for (int i = 0; i < 4; i++) {
        pk[i] = *(const s16x8*)(Kg + ((size_t)k0n + kr[i]) * DD + kc[i] * 8);
        pv[i] = *(const s16x8*)(Vg + (size_t)vd[i] * SS + k0n + vc[i] * 8);
      }
#pragma unroll
      for (int jt = 0; jt < 2; jt++)
#pragma unroll
        for (int rg = 0; rg < 4; rg++) pm[jt][rg] = Mg[rg * SS + k0n + jt * 16 + col];
    }

    // S = Q K^T (pre-scaled): 2 col-tiles x 8 d-chunks
    f32x4 st[2];
    __builtin_amdgcn_s_setprio(1);
#pragma unroll
    for (int jt = 0; jt < 2; jt++) {
      f32x4 s = f32x4{0.f, 0.f, 0.f, 0.f};
#pragma unroll
      for (int dc = 0; dc < 8; dc++) {
        s16x8 kb = *(const s16x8*)&Kl[(jt * 16 + col) * KROW + dc * 32 + quad * 8];
        s = __builtin_amdgcn_mfma_f32_16x16x32_bf16(qf[dc], kb, s, 0, 0, 0);
      }
      st[jt] = s;
    }
    __builtin_amdgcn_s_setprio(0);
    // mask (nonzero -> -1e9, post-scale, matching reference)
#pragma unroll
    for (int jt = 0; jt < 2; jt++)
#pragma unroll
      for (int rg = 0; rg < 4; rg++)
        if (mcur[jt][rg]) st[jt][rg] = -1e9f;

    // online softmax: per q-row (row = quad*4+rg), reduce over 16 col lanes
    float al[4];
#pragma unroll
    for (int rg = 0; rg < 4; rg++) {
      float v = fmaxf(st[0][rg], st[1][rg]);
      v = fmaxf(v, __shfl_xor(v, 1));
      v = fmaxf(v, __shfl_xor(v, 2));
      v = fmaxf(v, __shfl_xor(v, 4));
      v = fmaxf(v, __shfl_xor(v, 8));
      const float mn = fmaxf(m_i[rg], v);
      al[rg] = __expf(m_i[rg] - mn);
      m_i[rg] = mn;
    }
#pragma unroll
    for (int rg = 0; rg < 4; rg++) {
      const float p0 = __expf(st[0][rg] - m_i[rg]);
      const float p1 = __expf(st[1][rg] - m_i[rg]);
      st[0][rg] = p0; st[1][rg] = p1;
      float s2 = p0 + p1;
      s2 += __shfl_xor(s2, 1);
      s2 += __shfl_xor(s2, 2);
      s2 += __shfl_xor(s2, 4);
      s2 += __shfl_xor(s2, 8);
      l_i[rg] = l_i[rg] * al[rg] + s2;
    }
#pragma unroll
    for (int dt = 0; dt < 16; dt++)
#pragma unroll
      for (int rg = 0; rg < 4; rg++) Oc[dt][rg] *= al[rg];

    // P: C-layout -> LDS -> A-layout (per-wave region, same-wave dependency only)
#pragma unroll
    for (int jt = 0; jt < 2; jt++)
#pragma unroll
      for (int rg = 0; rg < 4; rg++)
        Pw[(quad * 4 + rg) * PROW + jt * 16 + col] = f2bf(st[jt][rg]);
    s16x8 pa = *(const s16x8*)&Pw[col * PROW + quad * 8];

    // O += P * V
    __builtin_amdgcn_s_setprio(1);
#pragma unroll
    for (int dt = 0; dt < 16; dt++) {
      s16x8 vb = *(const s16x8*)&Vl[(dt * 16 + col) * VROW + quad * 8];
      Oc[dt] = __builtin_amdgcn_mfma_f32_16x16x32_bf16(pa, vb, Oc[dt], 0, 0, 0);
    }
    __builtin_amdgcn_s_setprio(0);
  }

  // ---- 2-round merge of the 4 KV-split partials (exact online-softmax) ----
  float* ex = (float*)sm;
  // round 1: g1 -> pair slot 0, g3 -> pair slot 1; g0 merges 1, g2 merges 3
  __syncthreads();
  if (g & 1) {
    float* slot = ex + (size_t)((g >> 1) * 256 + w * 64 + lane) * XSTRIDE;
#pragma unroll
    for (int rg = 0; rg < 4; rg++) { slot[rg] = m_i[rg]; slot[4 + rg] = l_i[rg]; }
#pragma unroll
    for (int dt = 0; dt < 16; dt++) *(f32x4*)&slot[8 + dt * 4] = Oc[dt];
  }
  __syncthreads();
  if (!(g & 1)) {
    const float* slot = ex + (size_t)((g >> 1) * 256 + w * 64 + lane) * XSTRIDE;
    float a0[4], a1[4];
#pragma unroll
    for (int rg = 0; rg < 4; rg++) {
      const float m1 = slot[rg];
      const float l1 = slot[4 + rg];
      const float mm = fmaxf(m_i[rg], m1);
      a0[rg] = __expf(m_i[rg] - mm);
      a1[rg] = __expf(m1 - mm);
      m_i[rg] = mm;
      l_i[rg] = l_i[rg] * a0[rg] + l1 * a1[rg];
    }
#pragma unroll
    for (int dt = 0; dt < 16; dt++) {
      const f32x4 o1 = *(const f32x4*)&slot[8 + dt * 4];
#pragma unroll
      for (int rg = 0; rg < 4; rg++)
        Oc[dt][rg] = Oc[dt][rg] * a0[rg] + o1[rg] * a1[rg];
    }
  }
  // round 2: g2 -> slot area 0; g0 merges and stores
  __syncthreads();
  if (g == 2) {
    float* slot = ex + (size_t)(w * 64 + lane) * XSTRIDE;
#pragma unroll
    for (int rg = 0; rg < 4; rg++) { slot[rg] = m_i[rg]; slot[4 + rg] = l_i[rg]; }
#pragma unroll
    for (int dt = 0; dt < 16; dt++) *(f32x4*)&slot[8 + dt * 4] = Oc[dt];
  }
  __syncthreads();
  if (g == 0) {
    const float* slot = ex + (size_t)(w * 64 + lane) * XSTRIDE;
    float a0[4], a1[4], inv[4];
#pragma unroll
    for (int rg = 0; rg < 4; rg++) {
      const float m1 = slot[rg];
      const float l1 = slot[4 + rg];
      const float mm = fmaxf(m_i[rg], m1);
      a0[rg] = __expf(m_i[rg] - mm);
      a1[rg] = __expf(m1 - mm);
      inv[rg] = 1.0f / (l_i[rg] * a0[rg] + l1 * a1[rg]);
    }
    float* op = out + ((size_t)b * SS + qrow + quad * 4) * DD;
#pragma unroll
    for (int dt = 0; dt < 16; dt++) {
      const f32x4 o1 = *(const f32x4*)&slot[8 + dt * 4];
#pragma unroll
      for (int rg = 0; rg < 4; rg++)
        op[rg * DD + dt * 16 + col] = (Oc[dt][rg] * a0[rg] + o1[rg] * a1[rg]) * inv[rg];
    }
  }
}

extern "C" void kernel_launch(void* const* d_in, const int* in_sizes, int n_in,
                              void* d_out, int out_size, void* d_ws, size_t ws_size,
                              hipStream_t stream) {
  const float* X  = (const float*)d_in[0];
  const int* mask = (const int*)d_in[1];
  const float* Wq = (const float*)d_in[2];
  const float* bq = (const float*)d_in[3];
  const float* Wk = (const float*)d_in[4];
  const float* bk = (const float*)d_in[5];
  const float* Wv = (const float*)d_in[6];
  const float* bv = (const float*)d_in[7];
  float* out = (float*)d_out;

  ushort* base = (ushort*)d_ws;
  ushort* Xb = base;
  ushort* Wb = Xb + (size_t)BB * SS * DD;
  ushort* Qb = Wb + (size_t)3 * DD * DD;
  ushort* Kb = Qb + (size_t)BB * SS * DD;
  ushort* Vt = Kb + (size_t)BB * SS * DD;
  float* bias = (float*)(Vt + (size_t)BB * SS * DD);

  convert_kernel<<<1024, 256, 0, stream>>>(X, Wq, Wk, Wv, bq, bk, bv, Xb, Wb, bias);
  proj_gemm<<<dim3(128, 6), 256, 0, stream>>>(Xb, Wb, bias, Qb, Kb, Vt);
  attn_kernel<<<dim3(64, 4), 1024, 0, stream>>>(Qb, Kb, Vt, mask, out);
}

// Round 6
// 948.717 us; speedup vs baseline: 1.4931x; 1.4906x over previous
//
#include <hip/hip_runtime.h>
#include <hip/hip_bf16.h>
#include <stdint.h>

#define BB 4
#define SS 4096
#define DD 256

typedef __attribute__((ext_vector_type(4))) float f32x4;
typedef __attribute__((ext_vector_type(8))) short s16x8;

__device__ __forceinline__ ushort f2bf(float f) {
  __hip_bfloat16 h = __float2bfloat16(f);
  return __builtin_bit_cast(ushort, h);
}

// ---------------- kernel 1: fp32 -> bf16 pack ----------------
__global__ void convert_kernel(const float* __restrict__ X,
                               const float* __restrict__ Wq,
                               const float* __restrict__ Wk,
                               const float* __restrict__ Wv,
                               const float* __restrict__ bq,
                               const float* __restrict__ bk,
                               const float* __restrict__ bv,
                               ushort* __restrict__ Xb,
                               ushort* __restrict__ Wb,
                               float* __restrict__ bias) {
  int tid = blockIdx.x * blockDim.x + threadIdx.x;
  int stride = gridDim.x * blockDim.x;
  const int NX4 = (BB * SS * DD) / 4;
  for (int i = tid; i < NX4; i += stride) {
    float4 v = ((const float4*)X)[i];
    ushort4 o = { f2bf(v.x), f2bf(v.y), f2bf(v.z), f2bf(v.w) };
    ((ushort4*)Xb)[i] = o;
  }
  const int NW4 = (DD * DD) / 4;
  for (int i = tid; i < NW4; i += stride) {
    float4 a = ((const float4*)Wq)[i];
    float4 b = ((const float4*)Wk)[i];
    float4 c = ((const float4*)Wv)[i];
    ushort4 oa = { f2bf(a.x), f2bf(a.y), f2bf(a.z), f2bf(a.w) };
    ushort4 ob = { f2bf(b.x), f2bf(b.y), f2bf(b.z), f2bf(b.w) };
    ushort4 oc = { f2bf(c.x), f2bf(c.y), f2bf(c.z), f2bf(c.w) };
    ((ushort4*)Wb)[i]           = oa;
    ((ushort4*)Wb)[NW4 + i]     = ob;
    ((ushort4*)Wb)[2 * NW4 + i] = oc;
  }
  if (tid < DD) {
    bias[tid]          = bq[tid];
    bias[DD + tid]     = bk[tid];
    bias[2 * DD + tid] = bv[tid];
  }
}

// ---------------- kernel 2: fused QKV projection GEMM ----------------
#define LROW 40  // padded LDS row stride (bf16 elems); 80B = 20 dwords -> 2-way bank alias (free)

__global__ __launch_bounds__(256) void proj_gemm(const ushort* __restrict__ Xb,
                                                 const ushort* __restrict__ Wb,
                                                 const float* __restrict__ bias,
                                                 ushort* __restrict__ Qb,
                                                 ushort* __restrict__ Kb,
                                                 ushort* __restrict__ Vt) {
  __shared__ ushort Al[128 * LROW];
  __shared__ ushort Bl[128 * LROW];
  const int m0 = blockIdx.x * 128;
  const int n0 = blockIdx.y * 128;
  const int t = threadIdx.x;
  const int lane = t & 63;
  const int w = t >> 6;
  const int wr = w & 1, wc = w >> 1;
  const int col = lane & 15;
  const int quad = lane >> 4;

  f32x4 acc[4][4];
#pragma unroll
  for (int i = 0; i < 4; i++)
#pragma unroll
    for (int j = 0; j < 4; j++) acc[i][j] = f32x4{0.f, 0.f, 0.f, 0.f};

  const int ci0 = t, ci1 = 256 + t;
  const int r0 = ci0 >> 2, c0 = ci0 & 3;
  const int r1 = ci1 >> 2, c1 = ci1 & 3;

  s16x8 pa0 = *(const s16x8*)(Xb + (m0 + r0) * DD + c0 * 8);
  s16x8 pa1 = *(const s16x8*)(Xb + (m0 + r1) * DD + c1 * 8);
  s16x8 pb0 = *(const s16x8*)(Wb + (n0 + r0) * DD + c0 * 8);
  s16x8 pb1 = *(const s16x8*)(Wb + (n0 + r1) * DD + c1 * 8);

  for (int kk = 0; kk < DD; kk += 32) {
    __syncthreads();
    *(s16x8*)&Al[r0 * LROW + c0 * 8] = pa0;
    *(s16x8*)&Al[r1 * LROW + c1 * 8] = pa1;
    *(s16x8*)&Bl[r0 * LROW + c0 * 8] = pb0;
    *(s16x8*)&Bl[r1 * LROW + c1 * 8] = pb1;
    __syncthreads();
    const int kn = kk + 32;
    if (kn < DD) {
      pa0 = *(const s16x8*)(Xb + (m0 + r0) * DD + kn + c0 * 8);
      pa1 = *(const s16x8*)(Xb + (m0 + r1) * DD + kn + c1 * 8);
      pb0 = *(const s16x8*)(Wb + (n0 + r0) * DD + kn + c0 * 8);
      pb1 = *(const s16x8*)(Wb + (n0 + r1) * DD + kn + c1 * 8);
    }
    s16x8 af[4], bfr[4];
#pragma unroll
    for (int mi = 0; mi < 4; mi++)
      af[mi] = *(const s16x8*)&Al[(wr * 64 + mi * 16 + col) * LROW + quad * 8];
#pragma unroll
    for (int ni = 0; ni < 4; ni++)
      bfr[ni] = *(const s16x8*)&Bl[(wc * 64 + ni * 16 + col) * LROW + quad * 8];
#pragma unroll
    for (int mi = 0; mi < 4; mi++)
#pragma unroll
      for (int ni = 0; ni < 4; ni++)
        acc[mi][ni] = __builtin_amdgcn_mfma_f32_16x16x32_bf16(af[mi], bfr[ni], acc[mi][ni], 0, 0, 0);
  }

  const int region = n0 >> 8;  // 0=Q, 1=K, 2=V
#pragma unroll
  for (int mi = 0; mi < 4; mi++) {
    const int gm = m0 + wr * 64 + mi * 16 + quad * 4;
#pragma unroll
    for (int ni = 0; ni < 4; ni++) {
      const int gn = n0 + wc * 64 + ni * 16 + col;
      const float bb = bias[gn];
      f32x4 v = acc[mi][ni];
      if (region == 0) {
#pragma unroll
        for (int rg = 0; rg < 4; rg++)
          Qb[(gm + rg) * DD + gn] = f2bf((v[rg] + bb) * 0.015625f);  // exact /64
      } else if (region == 1) {
        const int d = gn - 256;
#pragma unroll
        for (int rg = 0; rg < 4; rg++)
          Kb[(gm + rg) * DD + d] = f2bf(v[rg] + bb);
      } else {
        const int d = gn - 512;
        const int b = gm >> 12;
        const int s = gm & (SS - 1);
        ushort4 o = { f2bf(v[0] + bb), f2bf(v[1] + bb), f2bf(v[2] + bb), f2bf(v[3] + bb) };
        *(ushort4*)&Vt[((size_t)(b << 8) + d) * SS + s] = o;
      }
    }
  }
}

// ---------------- kernel 3: flash attention ----------------
// Grid (64 qt, 4 b, 2 z): 512 blocks x 512 threads -> 2 blocks/CU, 16 waves/CU
// (4 waves/SIMD). Block z handles KV rows [z*2048, z*2048+2048) split over 2
// in-block KV groups (g handles 1024 kv each, merged via LDS exchange). The
// block then writes UNNORMALIZED merged O + (m,l): z=0 -> out (as scratch),
// z=1 -> O1 workspace; merge_kernel does the exact cross-z combine.
// NOTE: 1024-thread single-block variant is a dead end — hipcc pins a 64-VGPR
// budget at 1024 threads (R3-R5: accumulators spill, 4 GB scratch traffic,
// 5x regression) and neither __launch_bounds__(1024,4) nor
// amdgpu_waves_per_eu(4,4) lifts it. 512-thread blocks compile at ~108 VGPR
// (<=128 cap) with no spill (R2-proven).
#define NKT 32
#define KROW 260  // 520B = 130 dw, 130%32=2 -> 16 col-lanes hit 16 distinct banks
#define VROW 36   //  72B =  18 dw, stride 18%32: 16 lanes -> 16 distinct banks
#define PROW 36

#define KL_U (NKT * KROW)        // 8320 ushorts per group
#define VL_U (DD * VROW)         // 9216 per group
#define PL_U (16 * PROW)         // 576 per wave
#define VOFF (2 * KL_U)          // 16640
#define POFF (VOFF + 2 * VL_U)   // 35072
#define SM_U (POFF + 8 * PL_U)   // 39680 ushorts = 79360 B  (2 WGs/CU: 2x79360 <= 163840)

// exchange: 4 waves x 64 lanes x 72 f32 (m[4], l[4], O[64]) = 73728 B <= 79360 B
#define XSTRIDE 72

__global__ __launch_bounds__(512) void attn_kernel(const ushort* __restrict__ Qb,
                                                   const ushort* __restrict__ Kb,
                                                   const ushort* __restrict__ Vt,
                                                   const int* __restrict__ mask,
                                                   float* __restrict__ out,
                                                   float* __restrict__ O1,
                                                   float* __restrict__ Ml) {
  __shared__ __align__(16) ushort sm[SM_U];

  const int qt = blockIdx.x;  // 0..63
  const int b = blockIdx.y;   // 0..3
  const int z = blockIdx.z;   // 0..1 (KV half)
  const int t = threadIdx.x;
  const int g = t >> 8;       // in-block KV group: 0 or 1
  const int tg = t & 255;     // thread within group
  const int lane = t & 63;
  const int w = tg >> 6;      // row-wave within group: 0..3
  const int w8 = t >> 6;      // global wave: 0..7
  const int col = lane & 15;
  const int quad = lane >> 4;

  ushort* Kl = sm + g * KL_U;
  ushort* Vl = sm + VOFF + g * VL_U;
  ushort* Pw = sm + POFF + w8 * PL_U;

  const int q0 = qt * 64;
  const int qrow = q0 + w * 16;  // wave's first q row (within batch)

  // Q fragments (A-operand), pre-scaled by 1/64
  s16x8 qf[8];
  {
    const ushort* qp = Qb + ((size_t)b * SS + qrow + col) * DD + quad * 8;
#pragma unroll
    for (int dc = 0; dc < 8; dc++) qf[dc] = *(const s16x8*)(qp + dc * 32);
  }

  int kr[4], kc[4], vd[4], vc[4];
#pragma unroll
  for (int i = 0; i < 4; i++) {
    const int ci = i * 256 + tg;
    kr[i] = ci >> 5; kc[i] = ci & 31;  // K tile: 32 rows x 32 chunks(8)
    vd[i] = ci >> 2; vc[i] = ci & 3;   // Vt tile: 256 d-rows x 4 chunks(8)
  }

  const ushort* Kg = Kb + (size_t)b * SS * DD;
  const ushort* Vg = Vt + (size_t)b * DD * SS;
  const int* Mg = mask + ((size_t)b * SS + qrow + quad * 4) * SS;

  f32x4 Oc[16];
#pragma unroll
  for (int i = 0; i < 16; i++) Oc[i] = f32x4{0.f, 0.f, 0.f, 0.f};
  float m_i[4] = {-INFINITY, -INFINITY, -INFINITY, -INFINITY};
  float l_i[4] = {0.f, 0.f, 0.f, 0.f};

  const int NT2 = 1024 / NKT;             // 32 tiles per in-block group
  const int kb0 = z * 2048 + g * 1024;    // group's first kv position

  // prefetch this group's tile 0 into registers
  s16x8 pk[4], pv[4];
  int pm[2][4];
#pragma unroll
  for (int i = 0; i < 4; i++) {
    pk[i] = *(const s16x8*)(Kg + (size_t)(kb0 + kr[i]) * DD + kc[i] * 8);
    pv[i] = *(const s16x8*)(Vg + (size_t)vd[i] * SS + kb0 + vc[i] * 8);
  }
#pragma unroll
  for (int jt = 0; jt < 2; jt++)
#pragma unroll
    for (int rg = 0; rg < 4; rg++) pm[jt][rg] = Mg[rg * SS + kb0 + jt * 16 + col];

  for (int tt = 0; tt < NT2; tt++) {
    __syncthreads();
#pragma unroll
    for (int i = 0; i < 4; i++) {
      *(s16x8*)&Kl[kr[i] * KROW + kc[i] * 8] = pk[i];
      *(s16x8*)&Vl[vd[i] * VROW + vc[i] * 8] = pv[i];
    }
    __syncthreads();
    int mcur[2][4];
#pragma unroll
    for (int jt = 0; jt < 2; jt++)
#pragma unroll
      for (int rg = 0; rg < 4; rg++) mcur[jt][rg] = pm[jt][rg];
    if (tt + 1 < NT2) {
      const int k0n = kb0 + (tt + 1) * NKT;
#pragma unroll
      for (int i = 0; i < 4; i++) {
        pk[i] = *(const s16x8*)(Kg + ((size_t)k0n + kr[i]) * DD + kc[i] * 8);
        pv[i] = *(const s16x8*)(Vg + (size_t)vd[i] * SS + k0n + vc[i] * 8);
      }
#pragma unroll
      for (int jt = 0; jt < 2; jt++)
#pragma unroll
        for (int rg = 0; rg < 4; rg++) pm[jt][rg] = Mg[rg * SS + k0n + jt * 16 + col];
    }

    // S = Q K^T (pre-scaled): 2 col-tiles x 8 d-chunks
    f32x4 st[2];
    __builtin_amdgcn_s_setprio(1);
#pragma unroll
    for (int jt = 0; jt < 2; jt++) {
      f32x4 s = f32x4{0.f, 0.f, 0.f, 0.f};
#pragma unroll
      for (int dc = 0; dc < 8; dc++) {
        s16x8 kb = *(const s16x8*)&Kl[(jt * 16 + col) * KROW + dc * 32 + quad * 8];
        s = __builtin_amdgcn_mfma_f32_16x16x32_bf16(qf[dc], kb, s, 0, 0, 0);
      }
      st[jt] = s;
    }
    __builtin_amdgcn_s_setprio(0);
    // mask (nonzero -> -1e9, post-scale, matching reference)
#pragma unroll
    for (int jt = 0; jt < 2; jt++)
#pragma unroll
      for (int rg = 0; rg < 4; rg++)
        if (mcur[jt][rg]) st[jt][rg] = -1e9f;

    // online softmax: per q-row (row = quad*4+rg), reduce over 16 col lanes
    float al[4];
#pragma unroll
    for (int rg = 0; rg < 4; rg++) {
      float v = fmaxf(st[0][rg], st[1][rg]);
      v = fmaxf(v, __shfl_xor(v, 1));
      v = fmaxf(v, __shfl_xor(v, 2));
      v = fmaxf(v, __shfl_xor(v, 4));
      v = fmaxf(v, __shfl_xor(v, 8));
      const float mn = fmaxf(m_i[rg], v);
      al[rg] = __expf(m_i[rg] - mn);
      m_i[rg] = mn;
    }
#pragma unroll
    for (int rg = 0; rg < 4; rg++) {
      const float p0 = __expf(st[0][rg] - m_i[rg]);
      const float p1 = __expf(st[1][rg] - m_i[rg]);
      st[0][rg] = p0; st[1][rg] = p1;
      float s2 = p0 + p1;
      s2 += __shfl_xor(s2, 1);
      s2 += __shfl_xor(s2, 2);
      s2 += __shfl_xor(s2, 4);
      s2 += __shfl_xor(s2, 8);
      l_i[rg] = l_i[rg] * al[rg] + s2;
    }
#pragma unroll
    for (int dt = 0; dt < 16; dt++)
#pragma unroll
      for (int rg = 0; rg < 4; rg++) Oc[dt][rg] *= al[rg];

    // P: C-layout -> LDS -> A-layout (per-wave region, same-wave dependency only)
#pragma unroll
    for (int jt = 0; jt < 2; jt++)
#pragma unroll
      for (int rg = 0; rg < 4; rg++)
        Pw[(quad * 4 + rg) * PROW + jt * 16 + col] = f2bf(st[jt][rg]);
    s16x8 pa = *(const s16x8*)&Pw[col * PROW + quad * 8];

    // O += P * V
    __builtin_amdgcn_s_setprio(1);
#pragma unroll
    for (int dt = 0; dt < 16; dt++) {
      s16x8 vb = *(const s16x8*)&Vl[(dt * 16 + col) * VROW + quad * 8];
      Oc[dt] = __builtin_amdgcn_mfma_f32_16x16x32_bf16(pa, vb, Oc[dt], 0, 0, 0);
    }
    __builtin_amdgcn_s_setprio(0);
  }

  // ---- merge the two in-block KV-group partials (exact online-softmax) ----
  __syncthreads();  // everyone done with K/V LDS before reuse as exchange
  float* ex = (float*)sm;
  float* slot = ex + (size_t)(w * 64 + lane) * XSTRIDE;
  if (g == 1) {
#pragma unroll
    for (int rg = 0; rg < 4; rg++) { slot[rg] = m_i[rg]; slot[4 + rg] = l_i[rg]; }
#pragma unroll
    for (int dt = 0; dt < 16; dt++) *(f32x4*)&slot[8 + dt * 4] = Oc[dt];
  }
  __syncthreads();
  if (g == 0) {
    float a0[4], a1[4];
#pragma unroll
    for (int rg = 0; rg < 4; rg++) {
      const float m1 = slot[rg];
      const float l1 = slot[4 + rg];
      const float mm = fmaxf(m_i[rg], m1);
      a0[rg] = __expf(m_i[rg] - mm);
      a1[rg] = __expf(m1 - mm);
      m_i[rg] = mm;
      l_i[rg] = l_i[rg] * a0[rg] + l1 * a1[rg];
    }
    // unnormalized partial O for this KV half; z=0 -> out (scratch), z=1 -> O1
    float* op = (z ? O1 : out) + ((size_t)b * SS + qrow + quad * 4) * DD;
#pragma unroll
    for (int dt = 0; dt < 16; dt++) {
      const f32x4 o1 = *(const f32x4*)&slot[8 + dt * 4];
#pragma unroll
      for (int rg = 0; rg < 4; rg++)
        op[rg * DD + dt * 16 + col] = Oc[dt][rg] * a0[rg] + o1[rg] * a1[rg];
    }
    if (col == 0) {
      float2* pml = (float2*)Ml + (size_t)z * BB * SS + (size_t)b * SS + qrow + quad * 4;
#pragma unroll
      for (int rg = 0; rg < 4; rg++) pml[rg] = make_float2(m_i[rg], l_i[rg]);
    }
  }
}

// ---------------- kernel 4: cross-z softmax merge ----------------
// out = (O0*a0 + O1*a1) / (l0*a0 + l1*a1), a_z = exp(m_z - max(m0,m1)).
__global__ __launch_bounds__(256) void merge_kernel(const float* __restrict__ Ml,
                                                    const float* __restrict__ O1,
                                                    float* __restrict__ out) {
  const int row = blockIdx.x * 4 + (threadIdx.x >> 6);  // 0..BB*SS-1
  const int lane = threadIdx.x & 63;
  const float2 ml0 = ((const float2*)Ml)[row];
  const float2 ml1 = ((const float2*)Ml)[BB * SS + row];
  const float mm = fmaxf(ml0.x, ml1.x);
  const float a0 = __expf(ml0.x - mm);
  const float a1 = __expf(ml1.x - mm);
  const float inv = 1.0f / (ml0.y * a0 + ml1.y * a1);
  f32x4* po = (f32x4*)out + (size_t)row * 64 + lane;
  const f32x4 o0 = *po;
  const f32x4 o1 = ((const f32x4*)O1)[(size_t)row * 64 + lane];
  f32x4 r;
#pragma unroll
  for (int j = 0; j < 4; j++) r[j] = (o0[j] * a0 + o1[j] * a1) * inv;
  *po = r;
}

extern "C" void kernel_launch(void* const* d_in, const int* in_sizes, int n_in,
                              void* d_out, int out_size, void* d_ws, size_t ws_size,
                              hipStream_t stream) {
  const float* X  = (const float*)d_in[0];
  const int* mask = (const int*)d_in[1];
  const float* Wq = (const float*)d_in[2];
  const float* bq = (const float*)d_in[3];
  const float* Wk = (const float*)d_in[4];
  const float* bk = (const float*)d_in[5];
  const float* Wv = (const float*)d_in[6];
  const float* bv = (const float*)d_in[7];
  float* out = (float*)d_out;

  ushort* base = (ushort*)d_ws;
  ushort* Xb = base;                                   // 4,194,304 u
  ushort* Wb = Xb + (size_t)BB * SS * DD;              //   196,608 u
  ushort* Qb = Wb + (size_t)3 * DD * DD;
  ushort* Kb = Qb + (size_t)BB * SS * DD;
  ushort* Vt = Kb + (size_t)BB * SS * DD;
  float* bias = (float*)(Vt + (size_t)BB * SS * DD);   // 768 f32
  float* O1 = bias + 768;                              // 4,194,304 f32 (16.8 MB)
  float* Ml = O1 + (size_t)BB * SS * DD;               // 2*BB*SS float2 (0.26 MB)
  // total ws ~= 51 MB

  convert_kernel<<<1024, 256, 0, stream>>>(X, Wq, Wk, Wv, bq, bk, bv, Xb, Wb, bias);
  proj_gemm<<<dim3(128, 6), 256, 0, stream>>>(Xb, Wb, bias, Qb, Kb, Vt);
  attn_kernel<<<dim3(64, 4, 2), 512, 0, stream>>>(Qb, Kb, Vt, mask, out, O1, Ml);
  merge_kernel<<<(BB * SS) / 4, 256, 0, stream>>>(Ml, O1, out);
}

// Round 7
// 540.095 us; speedup vs baseline: 2.6227x; 1.7566x over previous
//
#include <hip/hip_runtime.h>
#include <hip/hip_bf16.h>
#include <stdint.h>

#define BB 4
#define SS 4096
#define DD 256

typedef __attribute__((ext_vector_type(4))) float f32x4;
typedef __attribute__((ext_vector_type(8))) short s16x8;

__device__ __forceinline__ ushort f2bf(float f) {
  __hip_bfloat16 h = __float2bfloat16(f);
  return __builtin_bit_cast(ushort, h);
}

// ---------------- kernel 1: fp32 -> bf16 pack ----------------
__global__ void convert_kernel(const float* __restrict__ X,
                               const float* __restrict__ Wq,
                               const float* __restrict__ Wk,
                               const float* __restrict__ Wv,
                               const float* __restrict__ bq,
                               const float* __restrict__ bk,
                               const float* __restrict__ bv,
                               ushort* __restrict__ Xb,
                               ushort* __restrict__ Wb,
                               float* __restrict__ bias) {
  int tid = blockIdx.x * blockDim.x + threadIdx.x;
  int stride = gridDim.x * blockDim.x;
  const int NX4 = (BB * SS * DD) / 4;
  for (int i = tid; i < NX4; i += stride) {
    float4 v = ((const float4*)X)[i];
    ushort4 o = { f2bf(v.x), f2bf(v.y), f2bf(v.z), f2bf(v.w) };
    ((ushort4*)Xb)[i] = o;
  }
  const int NW4 = (DD * DD) / 4;
  for (int i = tid; i < NW4; i += stride) {
    float4 a = ((const float4*)Wq)[i];
    float4 b = ((const float4*)Wk)[i];
    float4 c = ((const float4*)Wv)[i];
    ushort4 oa = { f2bf(a.x), f2bf(a.y), f2bf(a.z), f2bf(a.w) };
    ushort4 ob = { f2bf(b.x), f2bf(b.y), f2bf(b.z), f2bf(b.w) };
    ushort4 oc = { f2bf(c.x), f2bf(c.y), f2bf(c.z), f2bf(c.w) };
    ((ushort4*)Wb)[i]           = oa;
    ((ushort4*)Wb)[NW4 + i]     = ob;
    ((ushort4*)Wb)[2 * NW4 + i] = oc;
  }
  if (tid < DD) {
    bias[tid]          = bq[tid];
    bias[DD + tid]     = bk[tid];
    bias[2 * DD + tid] = bv[tid];
  }
}

// ---------------- kernel 2: fused QKV projection GEMM ----------------
#define LROW 40  // padded LDS row stride (bf16 elems); 80B: multiple of 16B (b128-safe)

__global__ __launch_bounds__(256) void proj_gemm(const ushort* __restrict__ Xb,
                                                 const ushort* __restrict__ Wb,
                                                 const float* __restrict__ bias,
                                                 ushort* __restrict__ Qb,
                                                 ushort* __restrict__ Kb,
                                                 ushort* __restrict__ Vt) {
  __shared__ ushort Al[128 * LROW];
  __shared__ ushort Bl[128 * LROW];
  const int m0 = blockIdx.x * 128;
  const int n0 = blockIdx.y * 128;
  const int t = threadIdx.x;
  const int lane = t & 63;
  const int w = t >> 6;
  const int wr = w & 1, wc = w >> 1;
  const int col = lane & 15;
  const int quad = lane >> 4;

  f32x4 acc[4][4];
#pragma unroll
  for (int i = 0; i < 4; i++)
#pragma unroll
    for (int j = 0; j < 4; j++) acc[i][j] = f32x4{0.f, 0.f, 0.f, 0.f};

  const int ci0 = t, ci1 = 256 + t;
  const int r0 = ci0 >> 2, c0 = ci0 & 3;
  const int r1 = ci1 >> 2, c1 = ci1 & 3;

  s16x8 pa0 = *(const s16x8*)(Xb + (m0 + r0) * DD + c0 * 8);
  s16x8 pa1 = *(const s16x8*)(Xb + (m0 + r1) * DD + c1 * 8);
  s16x8 pb0 = *(const s16x8*)(Wb + (n0 + r0) * DD + c0 * 8);
  s16x8 pb1 = *(const s16x8*)(Wb + (n0 + r1) * DD + c1 * 8);

  for (int kk = 0; kk < DD; kk += 32) {
    __syncthreads();
    *(s16x8*)&Al[r0 * LROW + c0 * 8] = pa0;
    *(s16x8*)&Al[r1 * LROW + c1 * 8] = pa1;
    *(s16x8*)&Bl[r0 * LROW + c0 * 8] = pb0;
    *(s16x8*)&Bl[r1 * LROW + c1 * 8] = pb1;
    __syncthreads();
    const int kn = kk + 32;
    if (kn < DD) {
      pa0 = *(const s16x8*)(Xb + (m0 + r0) * DD + kn + c0 * 8);
      pa1 = *(const s16x8*)(Xb + (m0 + r1) * DD + kn + c1 * 8);
      pb0 = *(const s16x8*)(Wb + (n0 + r0) * DD + kn + c0 * 8);
      pb1 = *(const s16x8*)(Wb + (n0 + r1) * DD + kn + c1 * 8);
    }
    s16x8 af[4], bfr[4];
#pragma unroll
    for (int mi = 0; mi < 4; mi++)
      af[mi] = *(const s16x8*)&Al[(wr * 64 + mi * 16 + col) * LROW + quad * 8];
#pragma unroll
    for (int ni = 0; ni < 4; ni++)
      bfr[ni] = *(const s16x8*)&Bl[(wc * 64 + ni * 16 + col) * LROW + quad * 8];
#pragma unroll
    for (int mi = 0; mi < 4; mi++)
#pragma unroll
      for (int ni = 0; ni < 4; ni++)
        acc[mi][ni] = __builtin_amdgcn_mfma_f32_16x16x32_bf16(af[mi], bfr[ni], acc[mi][ni], 0, 0, 0);
  }

  const int region = n0 >> 8;  // 0=Q, 1=K, 2=V
#pragma unroll
  for (int mi = 0; mi < 4; mi++) {
    const int gm = m0 + wr * 64 + mi * 16 + quad * 4;
#pragma unroll
    for (int ni = 0; ni < 4; ni++) {
      const int gn = n0 + wc * 64 + ni * 16 + col;
      const float bb = bias[gn];
      f32x4 v = acc[mi][ni];
      if (region == 0) {
#pragma unroll
        for (int rg = 0; rg < 4; rg++)
          Qb[(gm + rg) * DD + gn] = f2bf((v[rg] + bb) * 0.015625f);  // exact /64
      } else if (region == 1) {
        const int d = gn - 256;
#pragma unroll
        for (int rg = 0; rg < 4; rg++)
          Kb[(gm + rg) * DD + d] = f2bf(v[rg] + bb);
      } else {
        const int d = gn - 512;
        const int b = gm >> 12;
        const int s = gm & (SS - 1);
        ushort4 o = { f2bf(v[0] + bb), f2bf(v[1] + bb), f2bf(v[2] + bb), f2bf(v[3] + bb) };
        *(ushort4*)&Vt[((size_t)(b << 8) + d) * SS + s] = o;
      }
    }
  }
}

// ---------------- kernel 3: flash attention ----------------
// Grid (64 qt, 4 b, 2 z): 512 blocks x 512 threads. Block z handles KV rows
// [z*2048, z*2048+2048) split over 2 in-block KV groups; unnormalized partial
// O + (m,l) written per z, merged exactly by merge_kernel.
// ALIGNMENT RULE (R6 lesson): LDS row strides MUST be multiples of 8 ushorts
// (16 B). R6's KROW=260/VROW=36 made half the row bases 8B-aligned -> compiler
// split every ds_read/write_b128 into b64 pairs -> per-tile time ~3x (663us).
// Pad rows by +8 ushorts, never +4/+2.
#define NKT 32
#define KROW 264  // 528B, 16B-aligned (b128-safe)
#define VROW 32   //  64B, 16B-aligned
#define PROW 32   //  64B, 16B-aligned

#define KL_U (NKT * KROW)        // 8448 ushorts per group
#define VL_U (DD * VROW)         // 8192 per group
#define PL_U (16 * PROW)         // 512 per wave
#define VOFF (2 * KL_U)          // 16896
#define POFF (VOFF + 2 * VL_U)   // 33280
#define SM_U (POFF + 8 * PL_U)   // 37376 ushorts = 74752 B (2 blocks: 149504 <= 163840)

// exchange: 4 waves x 64 lanes x 72 f32 (m[4], l[4], O[64]) = 73728 B <= 74752 B
#define XSTRIDE 72

__global__ __launch_bounds__(512) void attn_kernel(const ushort* __restrict__ Qb,
                                                   const ushort* __restrict__ Kb,
                                                   const ushort* __restrict__ Vt,
                                                   const int* __restrict__ mask,
                                                   float* __restrict__ out,
                                                   float* __restrict__ O1,
                                                   float* __restrict__ Ml) {
  __shared__ __align__(16) ushort sm[SM_U];

  const int qt = blockIdx.x;  // 0..63
  const int b = blockIdx.y;   // 0..3
  const int z = blockIdx.z;   // 0..1 (KV half)
  const int t = threadIdx.x;
  const int g = t >> 8;       // in-block KV group: 0 or 1
  const int tg = t & 255;     // thread within group
  const int lane = t & 63;
  const int w = tg >> 6;      // row-wave within group: 0..3
  const int w8 = t >> 6;      // global wave: 0..7
  const int col = lane & 15;
  const int quad = lane >> 4;

  ushort* Kl = sm + g * KL_U;
  ushort* Vl = sm + VOFF + g * VL_U;
  ushort* Pw = sm + POFF + w8 * PL_U;

  const int q0 = qt * 64;
  const int qrow = q0 + w * 16;  // wave's first q row (within batch)

  // Q fragments (A-operand), pre-scaled by 1/64
  s16x8 qf[8];
  {
    const ushort* qp = Qb + ((size_t)b * SS + qrow + col) * DD + quad * 8;
#pragma unroll
    for (int dc = 0; dc < 8; dc++) qf[dc] = *(const s16x8*)(qp + dc * 32);
  }

  int kr[4], kc[4], vd[4], vc[4];
#pragma unroll
  for (int i = 0; i < 4; i++) {
    const int ci = i * 256 + tg;
    kr[i] = ci >> 5; kc[i] = ci & 31;  // K tile: 32 rows x 32 chunks(8)
    vd[i] = ci >> 2; vc[i] = ci & 3;   // Vt tile: 256 d-rows x 4 chunks(8)
  }

  const ushort* Kg = Kb + (size_t)b * SS * DD;
  const ushort* Vg = Vt + (size_t)b * DD * SS;
  const int* Mg = mask + ((size_t)b * SS + qrow + quad * 4) * SS;

  f32x4 Oc[16];
#pragma unroll
  for (int i = 0; i < 16; i++) Oc[i] = f32x4{0.f, 0.f, 0.f, 0.f};
  float m_i[4] = {-INFINITY, -INFINITY, -INFINITY, -INFINITY};
  float l_i[4] = {0.f, 0.f, 0.f, 0.f};

  const int NT2 = 1024 / NKT;             // 32 tiles per in-block group
  const int kb0 = z * 2048 + g * 1024;    // group's first kv position

  // prefetch this group's tile 0 into registers
  s16x8 pk[4], pv[4];
  int pm[2][4];
#pragma unroll
  for (int i = 0; i < 4; i++) {
    pk[i] = *(const s16x8*)(Kg + (size_t)(kb0 + kr[i]) * DD + kc[i] * 8);
    pv[i] = *(const s16x8*)(Vg + (size_t)vd[i] * SS + kb0 + vc[i] * 8);
  }
#pragma unroll
  for (int jt = 0; jt < 2; jt++)
#pragma unroll
    for (int rg = 0; rg < 4; rg++) pm[jt][rg] = Mg[rg * SS + kb0 + jt * 16 + col];

  for (int tt = 0; tt < NT2; tt++) {
    __syncthreads();
#pragma unroll
    for (int i = 0; i < 4; i++) {
      *(s16x8*)&Kl[kr[i] * KROW + kc[i] * 8] = pk[i];
      *(s16x8*)&Vl[vd[i] * VROW + vc[i] * 8] = pv[i];
    }
    __syncthreads();
    int mcur[2][4];
#pragma unroll
    for (int jt = 0; jt < 2; jt++)
#pragma unroll
      for (int rg = 0; rg < 4; rg++) mcur[jt][rg] = pm[jt][rg];
    if (tt + 1 < NT2) {
      const int k0n = kb0 + (tt + 1) * NKT;
#pragma unroll
      for (int i = 0; i < 4; i++) {
        pk[i] = *(const s16x8*)(Kg + ((size_t)k0n + kr[i]) * DD + kc[i] * 8);
        pv[i] = *(const s16x8*)(Vg + (size_t)vd[i] * SS + k0n + vc[i] * 8);
      }
#pragma unroll
      for (int jt = 0; jt < 2; jt++)
#pragma unroll
        for (int rg = 0; rg < 4; rg++) pm[jt][rg] = Mg[rg * SS + k0n + jt * 16 + col];
    }

    // S = Q K^T (pre-scaled): 2 col-tiles x 8 d-chunks
    f32x4 st[2];
    __builtin_amdgcn_s_setprio(1);
#pragma unroll
    for (int jt = 0; jt < 2; jt++) {
      f32x4 s = f32x4{0.f, 0.f, 0.f, 0.f};
#pragma unroll
      for (int dc = 0; dc < 8; dc++) {
        s16x8 kb = *(const s16x8*)&Kl[(jt * 16 + col) * KROW + dc * 32 + quad * 8];
        s = __builtin_amdgcn_mfma_f32_16x16x32_bf16(qf[dc], kb, s, 0, 0, 0);
      }
      st[jt] = s;
    }
    __builtin_amdgcn_s_setprio(0);
    // mask (nonzero -> -1e9, post-scale, matching reference)
#pragma unroll
    for (int jt = 0; jt < 2; jt++)
#pragma unroll
      for (int rg = 0; rg < 4; rg++)
        if (mcur[jt][rg]) st[jt][rg] = -1e9f;

    // online softmax: per q-row (row = quad*4+rg), reduce over 16 col lanes
    float al[4];
#pragma unroll
    for (int rg = 0; rg < 4; rg++) {
      float v = fmaxf(st[0][rg], st[1][rg]);
      v = fmaxf(v, __shfl_xor(v, 1));
      v = fmaxf(v, __shfl_xor(v, 2));
      v = fmaxf(v, __shfl_xor(v, 4));
      v = fmaxf(v, __shfl_xor(v, 8));
      const float mn = fmaxf(m_i[rg], v);
      al[rg] = __expf(m_i[rg] - mn);
      m_i[rg] = mn;
    }
#pragma unroll
    for (int rg = 0; rg < 4; rg++) {
      const float p0 = __expf(st[0][rg] - m_i[rg]);
      const float p1 = __expf(st[1][rg] - m_i[rg]);
      st[0][rg] = p0; st[1][rg] = p1;
      float s2 = p0 + p1;
      s2 += __shfl_xor(s2, 1);
      s2 += __shfl_xor(s2, 2);
      s2 += __shfl_xor(s2, 4);
      s2 += __shfl_xor(s2, 8);
      l_i[rg] = l_i[rg] * al[rg] + s2;
    }
#pragma unroll
    for (int dt = 0; dt < 16; dt++)
#pragma unroll
      for (int rg = 0; rg < 4; rg++) Oc[dt][rg] *= al[rg];

    // P: C-layout -> LDS -> A-layout (per-wave region, same-wave dependency only)
#pragma unroll
    for (int jt = 0; jt < 2; jt++)
#pragma unroll
      for (int rg = 0; rg < 4; rg++)
        Pw[(quad * 4 + rg) * PROW + jt * 16 + col] = f2bf(st[jt][rg]);
    s16x8 pa = *(const s16x8*)&Pw[col * PROW + quad * 8];

    // O += P * V
    __builtin_amdgcn_s_setprio(1);
#pragma unroll
    for (int dt = 0; dt < 16; dt++) {
      s16x8 vb = *(const s16x8*)&Vl[(dt * 16 + col) * VROW + quad * 8];
      Oc[dt] = __builtin_amdgcn_mfma_f32_16x16x32_bf16(pa, vb, Oc[dt], 0, 0, 0);
    }
    __builtin_amdgcn_s_setprio(0);
  }

  // ---- merge the two in-block KV-group partials (exact online-softmax) ----
  __syncthreads();  // everyone done with K/V LDS before reuse as exchange
  float* ex = (float*)sm;
  float* slot = ex + (size_t)(w * 64 + lane) * XSTRIDE;
  if (g == 1) {
#pragma unroll
    for (int rg = 0; rg < 4; rg++) { slot[rg] = m_i[rg]; slot[4 + rg] = l_i[rg]; }
#pragma unroll
    for (int dt = 0; dt < 16; dt++) *(f32x4*)&slot[8 + dt * 4] = Oc[dt];
  }
  __syncthreads();
  if (g == 0) {
    float a0[4], a1[4];
#pragma unroll
    for (int rg = 0; rg < 4; rg++) {
      const float m1 = slot[rg];
      const float l1 = slot[4 + rg];
      const float mm = fmaxf(m_i[rg], m1);
      a0[rg] = __expf(m_i[rg] - mm);
      a1[rg] = __expf(m1 - mm);
      m_i[rg] = mm;
      l_i[rg] = l_i[rg] * a0[rg] + l1 * a1[rg];
    }
    // unnormalized partial O for this KV half; z=0 -> out (scratch), z=1 -> O1
    float* op = (z ? O1 : out) + ((size_t)b * SS + qrow + quad * 4) * DD;
#pragma unroll
    for (int dt = 0; dt < 16; dt++) {
      const f32x4 o1 = *(const f32x4*)&slot[8 + dt * 4];
#pragma unroll
      for (int rg = 0; rg < 4; rg++)
        op[rg * DD + dt * 16 + col] = Oc[dt][rg] * a0[rg] + o1[rg] * a1[rg];
    }
    if (col == 0) {
      float2* pml = (float2*)Ml + (size_t)z * BB * SS + (size_t)b * SS + qrow + quad * 4;
#pragma unroll
      for (int rg = 0; rg < 4; rg++) pml[rg] = make_float2(m_i[rg], l_i[rg]);
    }
  }
}

// ---------------- kernel 4: cross-z softmax merge ----------------
// out = (O0*a0 + O1*a1) / (l0*a0 + l1*a1), a_z = exp(m_z - max(m0,m1)).
__global__ __launch_bounds__(256) void merge_kernel(const float* __restrict__ Ml,
                                                    const float* __restrict__ O1,
                                                    float* __restrict__ out) {
  const int row = blockIdx.x * 4 + (threadIdx.x >> 6);  // 0..BB*SS-1
  const int lane = threadIdx.x & 63;
  const float2 ml0 = ((const float2*)Ml)[row];
  const float2 ml1 = ((const float2*)Ml)[BB * SS + row];
  const float mm = fmaxf(ml0.x, ml1.x);
  const float a0 = __expf(ml0.x - mm);
  const float a1 = __expf(ml1.x - mm);
  const float inv = 1.0f / (ml0.y * a0 + ml1.y * a1);
  f32x4* po = (f32x4*)out + (size_t)row * 64 + lane;
  const f32x4 o0 = *po;
  const f32x4 o1 = ((const f32x4*)O1)[(size_t)row * 64 + lane];
  f32x4 r;
#pragma unroll
  for (int j = 0; j < 4; j++) r[j] = (o0[j] * a0 + o1[j] * a1) * inv;
  *po = r;
}

extern "C" void kernel_launch(void* const* d_in, const int* in_sizes, int n_in,
                              void* d_out, int out_size, void* d_ws, size_t ws_size,
                              hipStream_t stream) {
  const float* X  = (const float*)d_in[0];
  const int* mask = (const int*)d_in[1];
  const float* Wq = (const float*)d_in[2];
  const float* bq = (const float*)d_in[3];
  const float* Wk = (const float*)d_in[4];
  const float* bk = (const float*)d_in[5];
  const float* Wv = (const float*)d_in[6];
  const float* bv = (const float*)d_in[7];
  float* out = (float*)d_out;

  ushort* base = (ushort*)d_ws;
  ushort* Xb = base;                                   // 4,194,304 u
  ushort* Wb = Xb + (size_t)BB * SS * DD;              //   196,608 u
  ushort* Qb = Wb + (size_t)3 * DD * DD;
  ushort* Kb = Qb + (size_t)BB * SS * DD;
  ushort* Vt = Kb + (size_t)BB * SS * DD;
  float* bias = (float*)(Vt + (size_t)BB * SS * DD);   // 768 f32
  float* O1 = bias + 768;                              // 4,194,304 f32 (16.8 MB)
  float* Ml = O1 + (size_t)BB * SS * DD;               // 2*BB*SS float2 (0.26 MB)
  // total ws ~= 51 MB

  convert_kernel<<<1024, 256, 0, stream>>>(X, Wq, Wk, Wv, bq, bk, bv, Xb, Wb, bias);
  proj_gemm<<<dim3(128, 6), 256, 0, stream>>>(Xb, Wb, bias, Qb, Kb, Vt);
  attn_kernel<<<dim3(64, 4, 2), 512, 0, stream>>>(Qb, Kb, Vt, mask, out, O1, Ml);
  merge_kernel<<<(BB * SS) / 4, 256, 0, stream>>>(Ml, O1, out);
}

// Round 8
// 513.746 us; speedup vs baseline: 2.7572x; 1.0513x over previous
//
#include <hip/hip_runtime.h>
#include <hip/hip_bf16.h>
#include <stdint.h>

#define BB 4
#define SS 4096
#define DD 256

typedef __attribute__((ext_vector_type(4))) float f32x4;
typedef __attribute__((ext_vector_type(8))) short s16x8;

__device__ __forceinline__ ushort f2bf(float f) {
  __hip_bfloat16 h = __float2bfloat16(f);
  return __builtin_bit_cast(ushort, h);
}

// ---------------- kernel 1: fp32 -> bf16 pack ----------------
__global__ void convert_kernel(const float* __restrict__ X,
                               const float* __restrict__ Wq,
                               const float* __restrict__ Wk,
                               const float* __restrict__ Wv,
                               const float* __restrict__ bq,
                               const float* __restrict__ bk,
                               const float* __restrict__ bv,
                               ushort* __restrict__ Xb,
                               ushort* __restrict__ Wb,
                               float* __restrict__ bias) {
  int tid = blockIdx.x * blockDim.x + threadIdx.x;
  int stride = gridDim.x * blockDim.x;
  const int NX4 = (BB * SS * DD) / 4;
  for (int i = tid; i < NX4; i += stride) {
    float4 v = ((const float4*)X)[i];
    ushort4 o = { f2bf(v.x), f2bf(v.y), f2bf(v.z), f2bf(v.w) };
    ((ushort4*)Xb)[i] = o;
  }
  const int NW4 = (DD * DD) / 4;
  for (int i = tid; i < NW4; i += stride) {
    float4 a = ((const float4*)Wq)[i];
    float4 b = ((const float4*)Wk)[i];
    float4 c = ((const float4*)Wv)[i];
    ushort4 oa = { f2bf(a.x), f2bf(a.y), f2bf(a.z), f2bf(a.w) };
    ushort4 ob = { f2bf(b.x), f2bf(b.y), f2bf(b.z), f2bf(b.w) };
    ushort4 oc = { f2bf(c.x), f2bf(c.y), f2bf(c.z), f2bf(c.w) };
    ((ushort4*)Wb)[i]           = oa;
    ((ushort4*)Wb)[NW4 + i]     = ob;
    ((ushort4*)Wb)[2 * NW4 + i] = oc;
  }
  if (tid < DD) {
    bias[tid]          = bq[tid];
    bias[DD + tid]     = bk[tid];
    bias[2 * DD + tid] = bv[tid];
  }
}

// ---------------- kernel 2: fused QKV projection GEMM ----------------
#define LROW 40  // padded LDS row stride (bf16 elems); 80B: multiple of 16B (b128-safe)

__global__ __launch_bounds__(256) void proj_gemm(const ushort* __restrict__ Xb,
                                                 const ushort* __restrict__ Wb,
                                                 const float* __restrict__ bias,
                                                 ushort* __restrict__ Qb,
                                                 ushort* __restrict__ Kb,
                                                 ushort* __restrict__ Vt) {
  __shared__ ushort Al[128 * LROW];
  __shared__ ushort Bl[128 * LROW];
  const int m0 = blockIdx.x * 128;
  const int n0 = blockIdx.y * 128;
  const int t = threadIdx.x;
  const int lane = t & 63;
  const int w = t >> 6;
  const int wr = w & 1, wc = w >> 1;
  const int col = lane & 15;
  const int quad = lane >> 4;

  f32x4 acc[4][4];
#pragma unroll
  for (int i = 0; i < 4; i++)
#pragma unroll
    for (int j = 0; j < 4; j++) acc[i][j] = f32x4{0.f, 0.f, 0.f, 0.f};

  const int ci0 = t, ci1 = 256 + t;
  const int r0 = ci0 >> 2, c0 = ci0 & 3;
  const int r1 = ci1 >> 2, c1 = ci1 & 3;

  s16x8 pa0 = *(const s16x8*)(Xb + (m0 + r0) * DD + c0 * 8);
  s16x8 pa1 = *(const s16x8*)(Xb + (m0 + r1) * DD + c1 * 8);
  s16x8 pb0 = *(const s16x8*)(Wb + (n0 + r0) * DD + c0 * 8);
  s16x8 pb1 = *(const s16x8*)(Wb + (n0 + r1) * DD + c1 * 8);

  for (int kk = 0; kk < DD; kk += 32) {
    __syncthreads();
    *(s16x8*)&Al[r0 * LROW + c0 * 8] = pa0;
    *(s16x8*)&Al[r1 * LROW + c1 * 8] = pa1;
    *(s16x8*)&Bl[r0 * LROW + c0 * 8] = pb0;
    *(s16x8*)&Bl[r1 * LROW + c1 * 8] = pb1;
    __syncthreads();
    const int kn = kk + 32;
    if (kn < DD) {
      pa0 = *(const s16x8*)(Xb + (m0 + r0) * DD + kn + c0 * 8);
      pa1 = *(const s16x8*)(Xb + (m0 + r1) * DD + kn + c1 * 8);
      pb0 = *(const s16x8*)(Wb + (n0 + r0) * DD + kn + c0 * 8);
      pb1 = *(const s16x8*)(Wb + (n0 + r1) * DD + kn + c1 * 8);
    }
    s16x8 af[4], bfr[4];
#pragma unroll
    for (int mi = 0; mi < 4; mi++)
      af[mi] = *(const s16x8*)&Al[(wr * 64 + mi * 16 + col) * LROW + quad * 8];
#pragma unroll
    for (int ni = 0; ni < 4; ni++)
      bfr[ni] = *(const s16x8*)&Bl[(wc * 64 + ni * 16 + col) * LROW + quad * 8];
#pragma unroll
    for (int mi = 0; mi < 4; mi++)
#pragma unroll
      for (int ni = 0; ni < 4; ni++)
        acc[mi][ni] = __builtin_amdgcn_mfma_f32_16x16x32_bf16(af[mi], bfr[ni], acc[mi][ni], 0, 0, 0);
  }

  const int region = n0 >> 8;  // 0=Q, 1=K, 2=V
#pragma unroll
  for (int mi = 0; mi < 4; mi++) {
    const int gm = m0 + wr * 64 + mi * 16 + quad * 4;
#pragma unroll
    for (int ni = 0; ni < 4; ni++) {
      const int gn = n0 + wc * 64 + ni * 16 + col;
      const float bb = bias[gn];
      f32x4 v = acc[mi][ni];
      if (region == 0) {
#pragma unroll
        for (int rg = 0; rg < 4; rg++)
          Qb[(gm + rg) * DD + gn] = f2bf((v[rg] + bb) * 0.015625f);  // exact /64
      } else if (region == 1) {
        const int d = gn - 256;
#pragma unroll
        for (int rg = 0; rg < 4; rg++)
          Kb[(gm + rg) * DD + d] = f2bf(v[rg] + bb);
      } else {
        const int d = gn - 512;
        const int b = gm >> 12;
        const int s = gm & (SS - 1);
        ushort4 o = { f2bf(v[0] + bb), f2bf(v[1] + bb), f2bf(v[2] + bb), f2bf(v[3] + bb) };
        *(ushort4*)&Vt[((size_t)(b << 8) + d) * SS + s] = o;
      }
    }
  }
}

// ---------------- kernel 3: flash attention ----------------
// Grid (64 qt, 4 b, 2 z): 512 blocks x 512 threads. Block z handles KV rows
// [z*2048, z*2048+2048) over 2 in-block KV groups; partials merged in LDS,
// then cross-z by merge_kernel.
// LDS TIME-SHARING (R7 lesson): at 74.7 KB/block the scheduler still ran
// 1 block/CU (Occupancy 23%) despite 2x74.7 <= 160 KB; the only HW-verified
// co-residency point is 64 KB -> 2 blocks/CU. K is live only during QK^T and
// V only during PV, so they share ONE region (write K, barrier, QK^T, barrier,
// write V from regs, barrier, PV; 4 barriers/tile). LDS = 41,984 B/block.
// End-of-loop exchange (73.7 KB needed) runs in two half-rounds (36.9 KB).
// ALIGNMENT RULE (R6): LDS row strides must be multiples of 8 ushorts (16 B)
// or ds_*_b128 splits into b64 pairs (3x per-tile cost).
#define NKT 32
#define KROW 264   // 528B, 16B-aligned
#define VROW 32    //  64B, 16B-aligned
#define PROW 32

#define KVREG_U 8448             // max(K tile 32*264=8448, V tile 256*32=8192)
#define PL_U (16 * PROW)         // 512 per wave
#define POFF (2 * KVREG_U)       // 16896
#define SM_U (POFF + 8 * PL_U)   // 20992 ushorts = 41984 B (2 blocks: 83968)

// exchange slot: 72 f32 (m[4], l[4], O[64]); 2 waves/round: 128*72*4 = 36864 B
#define XSTRIDE 72

__global__ __launch_bounds__(512) void attn_kernel(const ushort* __restrict__ Qb,
                                                   const ushort* __restrict__ Kb,
                                                   const ushort* __restrict__ Vt,
                                                   const int* __restrict__ mask,
                                                   float* __restrict__ out,
                                                   float* __restrict__ O1,
                                                   float* __restrict__ Ml) {
  __shared__ __align__(16) ushort sm[SM_U];

  const int qt = blockIdx.x;  // 0..63
  const int b = blockIdx.y;   // 0..3
  const int z = blockIdx.z;   // 0..1 (KV half)
  const int t = threadIdx.x;
  const int g = t >> 8;       // in-block KV group: 0 or 1
  const int tg = t & 255;     // thread within group
  const int lane = t & 63;
  const int w = tg >> 6;      // row-wave within group: 0..3
  const int w8 = t >> 6;      // global wave: 0..7
  const int col = lane & 15;
  const int quad = lane >> 4;

  ushort* Kl = sm + g * KVREG_U;   // K and V time-share this region
  ushort* Vl = sm + g * KVREG_U;
  ushort* Pw = sm + POFF + w8 * PL_U;

  const int q0 = qt * 64;
  const int qrow = q0 + w * 16;  // wave's first q row (within batch)

  // Q fragments (A-operand), pre-scaled by 1/64
  s16x8 qf[8];
  {
    const ushort* qp = Qb + ((size_t)b * SS + qrow + col) * DD + quad * 8;
#pragma unroll
    for (int dc = 0; dc < 8; dc++) qf[dc] = *(const s16x8*)(qp + dc * 32);
  }

  int kr[4], kc[4], vd[4], vc[4];
#pragma unroll
  for (int i = 0; i < 4; i++) {
    const int ci = i * 256 + tg;
    kr[i] = ci >> 5; kc[i] = ci & 31;  // K tile: 32 rows x 32 chunks(8)
    vd[i] = ci >> 2; vc[i] = ci & 3;   // Vt tile: 256 d-rows x 4 chunks(8)
  }

  const ushort* Kg = Kb + (size_t)b * SS * DD;
  const ushort* Vg = Vt + (size_t)b * DD * SS;
  const int* Mg = mask + ((size_t)b * SS + qrow + quad * 4) * SS;

  f32x4 Oc[16];
#pragma unroll
  for (int i = 0; i < 16; i++) Oc[i] = f32x4{0.f, 0.f, 0.f, 0.f};
  float m_i[4] = {-INFINITY, -INFINITY, -INFINITY, -INFINITY};
  float l_i[4] = {0.f, 0.f, 0.f, 0.f};

  const int NT2 = 1024 / NKT;             // 32 tiles per in-block group
  const int kb0 = z * 2048 + g * 1024;    // group's first kv position

  // prefetch this group's tile 0 into registers
  s16x8 pk[4], pv[4];
  int pm[2][4];
#pragma unroll
  for (int i = 0; i < 4; i++) {
    pk[i] = *(const s16x8*)(Kg + (size_t)(kb0 + kr[i]) * DD + kc[i] * 8);
    pv[i] = *(const s16x8*)(Vg + (size_t)vd[i] * SS + kb0 + vc[i] * 8);
  }
#pragma unroll
  for (int jt = 0; jt < 2; jt++)
#pragma unroll
    for (int rg = 0; rg < 4; rg++) pm[jt][rg] = Mg[rg * SS + kb0 + jt * 16 + col];

  for (int tt = 0; tt < NT2; tt++) {
    __syncthreads();   // B1: prior PV reads of shared region done
#pragma unroll
    for (int i = 0; i < 4; i++)
      *(s16x8*)&Kl[kr[i] * KROW + kc[i] * 8] = pk[i];
    __syncthreads();   // B2: K tile visible
    int mcur[2][4];
#pragma unroll
    for (int jt = 0; jt < 2; jt++)
#pragma unroll
      for (int rg = 0; rg < 4; rg++) mcur[jt][rg] = pm[jt][rg];
    const int k0n = kb0 + (tt + 1) * NKT;
    if (tt + 1 < NT2) {
#pragma unroll
      for (int i = 0; i < 4; i++)
        pk[i] = *(const s16x8*)(Kg + ((size_t)k0n + kr[i]) * DD + kc[i] * 8);
#pragma unroll
      for (int jt = 0; jt < 2; jt++)
#pragma unroll
        for (int rg = 0; rg < 4; rg++) pm[jt][rg] = Mg[rg * SS + k0n + jt * 16 + col];
    }

    // S = Q K^T (pre-scaled): 2 col-tiles x 8 d-chunks
    f32x4 st[2];
    __builtin_amdgcn_s_setprio(1);
#pragma unroll
    for (int jt = 0; jt < 2; jt++) {
      f32x4 s = f32x4{0.f, 0.f, 0.f, 0.f};
#pragma unroll
      for (int dc = 0; dc < 8; dc++) {
        s16x8 kb = *(const s16x8*)&Kl[(jt * 16 + col) * KROW + dc * 32 + quad * 8];
        s = __builtin_amdgcn_mfma_f32_16x16x32_bf16(qf[dc], kb, s, 0, 0, 0);
      }
      st[jt] = s;
    }
    __builtin_amdgcn_s_setprio(0);
    // mask (nonzero -> -1e9, post-scale, matching reference)
#pragma unroll
    for (int jt = 0; jt < 2; jt++)
#pragma unroll
      for (int rg = 0; rg < 4; rg++)
        if (mcur[jt][rg]) st[jt][rg] = -1e9f;

    // online softmax: per q-row (row = quad*4+rg), reduce over 16 col lanes
    float al[4];
#pragma unroll
    for (int rg = 0; rg < 4; rg++) {
      float v = fmaxf(st[0][rg], st[1][rg]);
      v = fmaxf(v, __shfl_xor(v, 1));
      v = fmaxf(v, __shfl_xor(v, 2));
      v = fmaxf(v, __shfl_xor(v, 4));
      v = fmaxf(v, __shfl_xor(v, 8));
      const float mn = fmaxf(m_i[rg], v);
      al[rg] = __expf(m_i[rg] - mn);
      m_i[rg] = mn;
    }
#pragma unroll
    for (int rg = 0; rg < 4; rg++) {
      const float p0 = __expf(st[0][rg] - m_i[rg]);
      const float p1 = __expf(st[1][rg] - m_i[rg]);
      st[0][rg] = p0; st[1][rg] = p1;
      float s2 = p0 + p1;
      s2 += __shfl_xor(s2, 1);
      s2 += __shfl_xor(s2, 2);
      s2 += __shfl_xor(s2, 4);
      s2 += __shfl_xor(s2, 8);
      l_i[rg] = l_i[rg] * al[rg] + s2;
    }

    // P: C-layout -> LDS -> A-layout (own region, same-wave dependency only)
#pragma unroll
    for (int jt = 0; jt < 2; jt++)
#pragma unroll
      for (int rg = 0; rg < 4; rg++)
        Pw[(quad * 4 + rg) * PROW + jt * 16 + col] = f2bf(st[jt][rg]);
    s16x8 pa = *(const s16x8*)&Pw[col * PROW + quad * 8];

    // O rescale (VALU, overlaps other waves' phases)
#pragma unroll
    for (int dt = 0; dt < 16; dt++)
#pragma unroll
      for (int rg = 0; rg < 4; rg++) Oc[dt][rg] *= al[rg];

    __syncthreads();   // B3: all QK^T reads done; shared region free for V
#pragma unroll
    for (int i = 0; i < 4; i++)
      *(s16x8*)&Vl[vd[i] * VROW + vc[i] * 8] = pv[i];
    if (tt + 1 < NT2) {  // prefetch next V only after current V consumed
#pragma unroll
      for (int i = 0; i < 4; i++)
        pv[i] = *(const s16x8*)(Vg + (size_t)vd[i] * SS + k0n + vc[i] * 8);
    }
    __syncthreads();   // B4: V tile visible

    // O += P * V
    __builtin_amdgcn_s_setprio(1);
#pragma unroll
    for (int dt = 0; dt < 16; dt++) {
      s16x8 vb = *(const s16x8*)&Vl[(dt * 16 + col) * VROW + quad * 8];
      Oc[dt] = __builtin_amdgcn_mfma_f32_16x16x32_bf16(pa, vb, Oc[dt], 0, 0, 0);
    }
    __builtin_amdgcn_s_setprio(0);
  }

  // ---- merge the two in-block KV-group partials (exact online-softmax) ----
  // exchange region (36.9 KB) fits in LDS only 2 waves at a time: 2 rounds
  float* ex = (float*)sm;
#pragma unroll
  for (int rr = 0; rr < 2; rr++) {
    __syncthreads();
    if (g == 1 && (w >> 1) == rr) {
      float* slot = ex + (size_t)((w & 1) * 64 + lane) * XSTRIDE;
#pragma unroll
      for (int rg = 0; rg < 4; rg++) { slot[rg] = m_i[rg]; slot[4 + rg] = l_i[rg]; }
#pragma unroll
      for (int dt = 0; dt < 16; dt++) *(f32x4*)&slot[8 + dt * 4] = Oc[dt];
    }
    __syncthreads();
    if (g == 0 && (w >> 1) == rr) {
      const float* slot = ex + (size_t)((w & 1) * 64 + lane) * XSTRIDE;
      float a0[4], a1[4];
#pragma unroll
      for (int rg = 0; rg < 4; rg++) {
        const float m1 = slot[rg];
        const float l1 = slot[4 + rg];
        const float mm = fmaxf(m_i[rg], m1);
        a0[rg] = __expf(m_i[rg] - mm);
        a1[rg] = __expf(m1 - mm);
        m_i[rg] = mm;
        l_i[rg] = l_i[rg] * a0[rg] + l1 * a1[rg];
      }
#pragma unroll
      for (int dt = 0; dt < 16; dt++) {
        const f32x4 o1 = *(const f32x4*)&slot[8 + dt * 4];
#pragma unroll
        for (int rg = 0; rg < 4; rg++)
          Oc[dt][rg] = Oc[dt][rg] * a0[rg] + o1[rg] * a1[rg];
      }
    }
  }
  if (g == 0) {
    // unnormalized partial O for this KV half; z=0 -> out (scratch), z=1 -> O1
    float* op = (z ? O1 : out) + ((size_t)b * SS + qrow + quad * 4) * DD;
#pragma unroll
    for (int dt = 0; dt < 16; dt++) {
#pragma unroll
      for (int rg = 0; rg < 4; rg++)
        op[rg * DD + dt * 16 + col] = Oc[dt][rg];
    }
    if (col == 0) {
      float2* pml = (float2*)Ml + (size_t)z * BB * SS + (size_t)b * SS + qrow + quad * 4;
#pragma unroll
      for (int rg = 0; rg < 4; rg++) pml[rg] = make_float2(m_i[rg], l_i[rg]);
    }
  }
}

// ---------------- kernel 4: cross-z softmax merge ----------------
// out = (O0*a0 + O1*a1) / (l0*a0 + l1*a1), a_z = exp(m_z - max(m0,m1)).
__global__ __launch_bounds__(256) void merge_kernel(const float* __restrict__ Ml,
                                                    const float* __restrict__ O1,
                                                    float* __restrict__ out) {
  const int row = blockIdx.x * 4 + (threadIdx.x >> 6);  // 0..BB*SS-1
  const int lane = threadIdx.x & 63;
  const float2 ml0 = ((const float2*)Ml)[row];
  const float2 ml1 = ((const float2*)Ml)[BB * SS + row];
  const float mm = fmaxf(ml0.x, ml1.x);
  const float a0 = __expf(ml0.x - mm);
  const float a1 = __expf(ml1.x - mm);
  const float inv = 1.0f / (ml0.y * a0 + ml1.y * a1);
  f32x4* po = (f32x4*)out + (size_t)row * 64 + lane;
  const f32x4 o0 = *po;
  const f32x4 o1 = ((const f32x4*)O1)[(size_t)row * 64 + lane];
  f32x4 r;
#pragma unroll
  for (int j = 0; j < 4; j++) r[j] = (o0[j] * a0 + o1[j] * a1) * inv;
  *po = r;
}

extern "C" void kernel_launch(void* const* d_in, const int* in_sizes, int n_in,
                              void* d_out, int out_size, void* d_ws, size_t ws_size,
                              hipStream_t stream) {
  const float* X  = (const float*)d_in[0];
  const int* mask = (const int*)d_in[1];
  const float* Wq = (const float*)d_in[2];
  const float* bq = (const float*)d_in[3];
  const float* Wk = (const float*)d_in[4];
  const float* bk = (const float*)d_in[5];
  const float* Wv = (const float*)d_in[6];
  const float* bv = (const float*)d_in[7];
  float* out = (float*)d_out;

  ushort* base = (ushort*)d_ws;
  ushort* Xb = base;                                   // 4,194,304 u
  ushort* Wb = Xb + (size_t)BB * SS * DD;              //   196,608 u
  ushort* Qb = Wb + (size_t)3 * DD * DD;
  ushort* Kb = Qb + (size_t)BB * SS * DD;
  ushort* Vt = Kb + (size_t)BB * SS * DD;
  float* bias = (float*)(Vt + (size_t)BB * SS * DD);   // 768 f32
  float* O1 = bias + 768;                              // 4,194,304 f32 (16.8 MB)
  float* Ml = O1 + (size_t)BB * SS * DD;               // 2*BB*SS float2 (0.26 MB)
  // total ws ~= 51 MB

  convert_kernel<<<1024, 256, 0, stream>>>(X, Wq, Wk, Wv, bq, bk, bv, Xb, Wb, bias);
  proj_gemm<<<dim3(128, 6), 256, 0, stream>>>(Xb, Wb, bias, Qb, Kb, Vt);
  attn_kernel<<<dim3(64, 4, 2), 512, 0, stream>>>(Qb, Kb, Vt, mask, out, O1, Ml);
  merge_kernel<<<(BB * SS) / 4, 256, 0, stream>>>(Ml, O1, out);
}